// Round 14
// baseline (262.265 us; speedup 1.0000x reference)
//
#include <hip/hip_runtime.h>
#include <hip/hip_bf16.h>

#define DIMN 2048
#define NQKV 6144
#define NH 16
#define HD 128
#define BSZ 2
#define SEQ 2048
#define ROWS (BSZ*SEQ)   // 4096

typedef short short8 __attribute__((ext_vector_type(8)));
typedef float f32x4 __attribute__((ext_vector_type(4)));
typedef float f32x16 __attribute__((ext_vector_type(16)));

__device__ __forceinline__ unsigned short f2bf(float f) {
    __hip_bfloat16 h = __float2bfloat16(f);
    unsigned short u; __builtin_memcpy(&u, &h, 2); return u;
}

__device__ __forceinline__ void gld_lds16(const void* g, void* l) {
    __builtin_amdgcn_global_load_lds(
        (const __attribute__((address_space(1))) void*)g,
        (__attribute__((address_space(3))) void*)l, 16, 0, 0);
}

// ---------------- fused f32 -> bf16 converts ----------------
__global__ void cvt_all(const float* __restrict__ x, const float* __restrict__ wq,
                        const float* __restrict__ wk, const float* __restrict__ wv,
                        const float* __restrict__ wo,
                        unsigned short* __restrict__ Xb, unsigned short* __restrict__ Wcat,
                        unsigned short* __restrict__ Wo2) {
    int bid = blockIdx.x;
    const float* in; unsigned short* out; int base;
    if      (bid <  8192) { in = x;  out = Xb;             base = bid; }
    else if (bid < 12288) { in = wq; out = Wcat;           base = bid - 8192; }
    else if (bid < 16384) { in = wk; out = Wcat + 4194304; base = bid - 12288; }
    else if (bid < 20480) { in = wv; out = Wcat + 8388608; base = bid - 16384; }
    else                  { in = wo; out = Wo2;            base = bid - 20480; }
    int i = (base * 256 + threadIdx.x) * 4;
    float4 v = *(const float4*)(in + i);
    ushort4 o; o.x = f2bf(v.x); o.y = f2bf(v.y); o.z = f2bf(v.z); o.w = f2bf(v.w);
    *(ushort4*)(out + i) = o;
}

// ================= m97-style 128x128 GEMM, 32x32x16 MFMA (QKV) =================
// r13 change vs r12 (single variable in this kernel): 16x16x32 -> 32x32x16 MFMA.
// Per 64x64 wave-tile per K-tile: 16 MFMA @8cy = 128cy matrix-pipe (was 32 @4.85 = 155cy,
// m119: 32x32 ubench +15%), same ds_read count/bytes, half the MFMA issue slots ->
// attacks r12's measured VALUBusy 46.8% / MfmaUtil 31.7%.
// A/B operand layout (family-consistent w/ verified 16x16x32): row = l&31, k = (l>>5)*8+i.
// C/D layout (HW-verified m74/m101): col = lane&31, row = (reg&3)+8*(reg>>2)+4*(lane>>5).
// Swizzle (verified r6-r12): physical col16 = logical ^ (row&7); pre-swizzled source.
__global__ __launch_bounds__(256) void gemm97q(
    const unsigned short* __restrict__ A, int lda,
    const unsigned short* __restrict__ B, int ldb,
    const float* __restrict__ b0, const float* __restrict__ b1, const float* __restrict__ b2,
    const float* __restrict__ fcos, const float* __restrict__ fsin,
    unsigned short* __restrict__ C, int ldc, int K)
{
    __shared__ __align__(16) unsigned short As[128 * 64];  // 16 KB
    __shared__ __align__(16) unsigned short Bs[128 * 64];  // 16 KB

    const int t    = threadIdx.x;
    const int l    = t & 63;
    const int w    = t >> 6;
    const int wr   = w >> 1, wc = w & 1;
    const int lrow = l & 31;    // row/col within 32x32 fragment
    const int lk   = l >> 5;    // k-group (0..1)

    // chunked XCD map: each XCD owns an n-stripe (B panel 3MB -> L2-resident)
    const int xcd = blockIdx.x & 7;
    const int j   = blockIdx.x >> 3;
    const int nt  = xcd * 6 + j % 6;   // 48 n-tiles
    const int mt  = j / 6;             // 32 m-tiles
    const int m0 = mt * 128;
    const int n0 = nt * 128;

    // staging source (pre-swizzled col; gld_lds dest linear)
    const int srow = t >> 3;                         // 0..31
    const int scol = ((t & 7) ^ (srow & 7)) * 8;
    const unsigned short* aS = A + (size_t)(m0 + srow) * lda + scol;
    const unsigned short* bS = B + (size_t)(n0 + srow) * ldb + scol;

    f32x16 acc[2][2] = {};

    for (int k0 = 0; k0 < K; k0 += 64) {
        __syncthreads();   // WAR: previous iteration's reads done
        #pragma unroll
        for (int r = 0; r < 4; ++r) {
            gld_lds16(aS + (size_t)(r * 32) * lda + k0, &As[r * 2048 + t * 8]);
            gld_lds16(bS + (size_t)(r * 32) * ldb + k0, &Bs[r * 2048 + t * 8]);
        }
        __syncthreads();   // compiler drains vmcnt(0) before barrier: data visible
        #pragma unroll
        for (int ks = 0; ks < 4; ++ks) {  // 4 k-steps of 16
            const int co = (((ks << 1) | lk) ^ (l & 7)) * 8;   // swizzled col offset
            short8 a[2], b[2];
            #pragma unroll
            for (int mi = 0; mi < 2; ++mi)
                a[mi] = *(const short8*)&As[(wr * 64 + mi * 32 + lrow) * 64 + co];
            #pragma unroll
            for (int ni = 0; ni < 2; ++ni)
                b[ni] = *(const short8*)&Bs[(wc * 64 + ni * 32 + lrow) * 64 + co];
            #pragma unroll
            for (int mi = 0; mi < 2; ++mi)
                #pragma unroll
                for (int ni = 0; ni < 2; ++ni)
                    acc[mi][ni] = __builtin_amdgcn_mfma_f32_32x32x16_bf16(a[mi], b[ni], acc[mi][ni], 0, 0, 0);
        }
    }

    // ---- epilogue: QKV region bias + fused RoPE (cols < 4096), bf16 store
    #pragma unroll
    for (int mi = 0; mi < 2; ++mi) {
        #pragma unroll
        for (int ni = 0; ni < 2; ++ni) {
            const int cg = n0 + wc * 64 + ni * 32 + lrow;
            #pragma unroll
            for (int reg = 0; reg < 16; ++reg) {
                const int r = m0 + wr * 64 + mi * 32 + (reg & 3) + 8 * (reg >> 2) + 4 * lk;
                float v = acc[mi][ni][reg];
                v += (cg < 2048) ? b0[cg] : ((cg < 4096) ? b1[cg - 2048] : b2[cg - 4096]);
                if (cg < 4096) {  // block-uniform branch: RoPE on Q and K
                    const int s = r & (SEQ - 1);
                    const int i = (cg >> 1) & 63;
                    const float cs = fcos[s * 64 + i];
                    const float sn = fsin[s * 64 + i];
                    const float p  = __shfl_xor(v, 1);
                    v = (l & 1) ? (p * sn + v * cs) : (v * cs - p * sn);
                }
                C[(size_t)r * ldc + cg] = f2bf(v);
            }
        }
    }
}

// ================= 256x256 de-convoyed GEMM (r11, proven best for out-GEMM) ==========
__global__ __launch_bounds__(512, 2) void gemm256o(
    const unsigned short* __restrict__ A, int lda,
    const unsigned short* __restrict__ B, int ldb,
    const float* __restrict__ b0,
    float* __restrict__ C, int ldc, int K)
{
    __shared__ __align__(16) unsigned short As[32768];  // 64 KB: [2buf][2half][128][64]
    __shared__ __align__(16) unsigned short Bs[32768];  // 64 KB

    const int t  = threadIdx.x;
    const int l  = t & 63;
    const int w  = t >> 6;
    const int wr = w >> 2;
    const int wc = w & 3;
    const int fr = l & 15, fq = l >> 4;

    const int xcd = blockIdx.x & 7;
    const int j   = blockIdx.x >> 3;
    const int mt  = (xcd >> 1) * 4 + (j >> 2);
    const int nt  = (xcd & 1) * 4 + (j & 3);
    const int m0 = mt * 256;
    const int n0 = nt * 256;

    const unsigned short* Bsel = B;
    if (m0 >= 2048) Bsel += (size_t)2048 * 2048;  // per-batch W2

    const int srow = t >> 3;
    const int scol = ((t & 7) ^ (srow & 7)) * 8;
    const unsigned short* aS = A    + (size_t)(m0 + srow) * lda + scol;
    const unsigned short* bS = Bsel + (size_t)(n0 + srow) * ldb + scol;

#define STG_A(KT, H) do { \
    const unsigned short* s_ = aS + (size_t)(H) * 128 * lda + (size_t)(KT) * 64; \
    gld_lds16(s_,                    &As[(((KT) & 1) << 14) + ((H) << 13) + t * 8]); \
    gld_lds16(s_ + (size_t)64 * lda, &As[(((KT) & 1) << 14) + ((H) << 13) + 4096 + t * 8]); \
  } while (0)
#define STG_B(KT, H) do { \
    const unsigned short* s_ = bS + (size_t)(H) * 128 * ldb + (size_t)(KT) * 64; \
    gld_lds16(s_,                    &Bs[(((KT) & 1) << 14) + ((H) << 13) + t * 8]); \
    gld_lds16(s_ + (size_t)64 * ldb, &Bs[(((KT) & 1) << 14) + ((H) << 13) + 4096 + t * 8]); \
  } while (0)

    const int cK0 = (fq ^ (fr & 7)) * 8;
    const int cK1 = ((4 + fq) ^ (fr & 7)) * 8;
    const int aB0 = wr * 8192 + fr * 64;
    const int bB0 = wc * 4096 + fr * 64;

    const unsigned aA0 = (unsigned)(size_t)&As[aB0 + cK0];
    const unsigned aA1 = (unsigned)(size_t)&As[aB0 + cK1];
    const unsigned bA0 = (unsigned)(size_t)&Bs[bB0 + cK0];
    const unsigned bA1 = (unsigned)(size_t)&Bs[bB0 + cK1];

    short8 aF[4][2], bF0[2][2], bF1[2][2];
    f32x4  acc[8][4] = {};

#define DSR(dst, areg, OFF) \
    asm volatile("ds_read_b128 %0, %1 offset:%2" : "=v"(dst) : "v"(areg), "n"(OFF))

#define RD_A(DDB, QM) do { \
    DSR(aF[0][0], aA0, (DDB) + (QM) * 8192 + 0);    DSR(aF[0][1], aA1, (DDB) + (QM) * 8192 + 0); \
    DSR(aF[1][0], aA0, (DDB) + (QM) * 8192 + 2048); DSR(aF[1][1], aA1, (DDB) + (QM) * 8192 + 2048); \
    DSR(aF[2][0], aA0, (DDB) + (QM) * 8192 + 4096); DSR(aF[2][1], aA1, (DDB) + (QM) * 8192 + 4096); \
    DSR(aF[3][0], aA0, (DDB) + (QM) * 8192 + 6144); DSR(aF[3][1], aA1, (DDB) + (QM) * 8192 + 6144); \
  } while (0)
#define RD_B(DDB, QN, BF) do { \
    DSR(BF[0][0], bA0, (DDB) + (QN) * 4096 + 0);    DSR(BF[0][1], bA1, (DDB) + (QN) * 4096 + 0); \
    DSR(BF[1][0], bA0, (DDB) + (QN) * 4096 + 2048); DSR(BF[1][1], bA1, (DDB) + (QN) * 4096 + 2048); \
  } while (0)

#define BAR() asm volatile("s_barrier" ::: "memory")

#define MM(QM, QN, BF) do { \
    _Pragma("unroll") for (int m2 = 0; m2 < 4; ++m2) \
      _Pragma("unroll") for (int n2 = 0; n2 < 2; ++n2) { \
        acc[(QM)*4+m2][(QN)*2+n2] = __builtin_amdgcn_mfma_f32_16x16x32_bf16( \
            aF[m2][0], BF[n2][0], acc[(QM)*4+m2][(QN)*2+n2], 0, 0, 0); \
        acc[(QM)*4+m2][(QN)*2+n2] = __builtin_amdgcn_mfma_f32_16x16x32_bf16( \
            aF[m2][1], BF[n2][1], acc[(QM)*4+m2][(QN)*2+n2], 0, 0, 0); } \
  } while (0)

#define TILE(KT, DDB) do { \
    if ((KT) + 1 < ktT) { \
        STG_A((KT) + 1, 0); STG_A((KT) + 1, 1); \
        STG_B((KT) + 1, 0); STG_B((KT) + 1, 1); \
    } \
    RD_A(DDB, 0); RD_B(DDB, 0, bF0); RD_B(DDB, 1, bF1); \
    asm volatile("s_waitcnt lgkmcnt(4)"); \
    __builtin_amdgcn_sched_barrier(0); \
    __builtin_amdgcn_s_setprio(1); \
    MM(0, 0, bF0); \
    asm volatile("s_waitcnt lgkmcnt(0)"); \
    __builtin_amdgcn_sched_barrier(0); \
    MM(0, 1, bF1); \
    __builtin_amdgcn_s_setprio(0); \
    RD_A(DDB, 1); \
    asm volatile("s_waitcnt lgkmcnt(0)"); \
    __builtin_amdgcn_sched_barrier(0); \
    __builtin_amdgcn_s_setprio(1); \
    MM(1, 0, bF0); MM(1, 1, bF1); \
    __builtin_amdgcn_s_setprio(0); \
    asm volatile("s_waitcnt vmcnt(0)"); \
    __builtin_amdgcn_sched_barrier(0); \
    BAR(); \
  } while (0)

    const int ktT = K >> 6;   // 32

    STG_A(0, 0); STG_A(0, 1);
    STG_B(0, 0); STG_B(0, 1);
    asm volatile("s_waitcnt vmcnt(0)");
    __builtin_amdgcn_sched_barrier(0);
    BAR();

    for (int kt = 0; kt < ktT; kt += 2) {
        TILE(kt, 0);
        TILE(kt + 1, 32768);
    }

#undef TILE
#undef MM
#undef BAR
#undef RD_A
#undef RD_B
#undef DSR
#undef STG_A
#undef STG_B

    #pragma unroll
    for (int mi = 0; mi < 8; ++mi) {
        #pragma unroll
        for (int ni = 0; ni < 4; ++ni) {
            #pragma unroll
            for (int j2 = 0; j2 < 4; ++j2) {
                const int r  = m0 + wr * 128 + mi * 16 + fq * 4 + j2;
                const int cg = n0 + wc * 64 + ni * 16 + fr;
                C[(size_t)r * ldc + cg] = acc[mi][ni][j2] + b0[cg];
            }
        }
    }
}

// ---------------- 128x128 GEMM core (small GEMMs) ----------------
template<int OUT_BF16, int HAS_BIAS>
__device__ __forceinline__ void gemm_tile_core(
    const unsigned short* __restrict__ A, int lda,
    const unsigned short* __restrict__ B, int ldb,
    const float* __restrict__ bias,
    void* __restrict__ Cptr, int ldc, int K)
{
    __shared__ __align__(16) unsigned short As[128 * 64];
    __shared__ __align__(16) unsigned short Bs[128 * 64];

    const int t  = threadIdx.x;
    const int l  = t & 63;
    const int w  = t >> 6;
    const int wr = w >> 1, wc = w & 1;
    const int fr = l & 15, fq = l >> 4;

    f32x4 acc[4][4] = {};

    const int srow = t >> 3;
    const int scol = (t & 7) * 8;

    for (int k0 = 0; k0 < K; k0 += 64) {
        __syncthreads();
        #pragma unroll
        for (int r = 0; r < 4; ++r) {
            gld_lds16(A + (size_t)(r * 32 + srow) * lda + k0 + scol, &As[(r * 32 + srow) * 64 + scol]);
            gld_lds16(B + (size_t)(r * 32 + srow) * ldb + k0 + scol, &Bs[(r * 32 + srow) * 64 + scol]);
        }
        __syncthreads();
        #pragma unroll
        for (int kk = 0; kk < 2; ++kk) {
            short8 a[4], b[4];
            #pragma unroll
            for (int mi = 0; mi < 4; ++mi)
                a[mi] = *(const short8*)&As[(wr * 64 + mi * 16 + fr) * 64 + kk * 32 + fq * 8];
            #pragma unroll
            for (int ni = 0; ni < 4; ++ni)
                b[ni] = *(const short8*)&Bs[(wc * 64 + ni * 16 + fr) * 64 + kk * 32 + fq * 8];
            #pragma unroll
            for (int mi = 0; mi < 4; ++mi)
                #pragma unroll
                for (int ni = 0; ni < 4; ++ni)
                    acc[mi][ni] = __builtin_amdgcn_mfma_f32_16x16x32_bf16(a[mi], b[ni], acc[mi][ni], 0, 0, 0);
        }
    }

    #pragma unroll
    for (int mi = 0; mi < 4; ++mi) {
        #pragma unroll
        for (int ni = 0; ni < 4; ++ni) {
            #pragma unroll
            for (int j = 0; j < 4; ++j) {
                int rr = wr * 64 + mi * 16 + fq * 4 + j;
                int cc = wc * 64 + ni * 16 + fr;
                float v = acc[mi][ni][j];
                if (HAS_BIAS) v += bias[cc];
                if (OUT_BF16) ((unsigned short*)Cptr)[(size_t)rr * ldc + cc] = f2bf(v);
                else          ((float*)Cptr)[(size_t)rr * ldc + cc] = v;
            }
        }
    }
}

// ---------------- K^T/V partials ----------------
__global__ __launch_bounds__(256) void ktv_kernel(
    const unsigned short* __restrict__ QKV, float* __restrict__ part)
{
    const int ks = blockIdx.x;
    const int bh = blockIdx.y;
    const int b = bh >> 4, h = bh & 15;
    const unsigned short* Kbase = QKV + (size_t)(b * SEQ + ks * 256) * NQKV + 2048 + h * HD;
    const unsigned short* Vbase = QKV + (size_t)(b * SEQ + ks * 256) * NQKV + 4096 + h * HD;

    __shared__ __align__(16) unsigned short Ks_[64 * 128];
    __shared__ __align__(16) unsigned short Vs_[64 * 128];

    const int t  = threadIdx.x;
    const int l  = t & 63;
    const int w  = t >> 6;
    const int wr = w >> 1, wc = w & 1;
    const int fr = l & 15, fq = l >> 4;

    f32x4 acc[4][4] = {};

    const int srow = t >> 4;
    const int scol = (t & 15) * 8;

    for (int sc = 0; sc < 4; ++sc) {
        __syncthreads();
        #pragma unroll
        for (int r = 0; r < 4; ++r) {
            gld_lds16(Kbase + (size_t)(sc * 64 + r * 16 + srow) * NQKV + scol, &Ks_[(r * 16 + srow) * 128 + scol]);
            gld_lds16(Vbase + (size_t)(sc * 64 + r * 16 + srow) * NQKV + scol, &Vs_[(r * 16 + srow) * 128 + scol]);
        }
        __syncthreads();
        #pragma unroll
        for (int kk = 0; kk < 2; ++kk) {
            short8 a[4], bb[4];
            #pragma unroll
            for (int mi = 0; mi < 4; ++mi)
                #pragma unroll
                for (int i = 0; i < 8; ++i)
                    a[mi][i] = (short)Ks_[(kk * 32 + fq * 8 + i) * 128 + wr * 64 + mi * 16 + fr];
            #pragma unroll
            for (int ni = 0; ni < 4; ++ni)
                #pragma unroll
                for (int i = 0; i < 8; ++i)
                    bb[ni][i] = (short)Vs_[(kk * 32 + fq * 8 + i) * 128 + wc * 64 + ni * 16 + fr];
            #pragma unroll
            for (int mi = 0; mi < 4; ++mi)
                #pragma unroll
                for (int ni = 0; ni < 4; ++ni)
                    acc[mi][ni] = __builtin_amdgcn_mfma_f32_16x16x32_bf16(a[mi], bb[ni], acc[mi][ni], 0, 0, 0);
        }
    }

    float* base = part + ((size_t)bh * 8 + ks) * 16384;
    #pragma unroll
    for (int mi = 0; mi < 4; ++mi)
        #pragma unroll
        for (int ni = 0; ni < 4; ++ni)
            #pragma unroll
            for (int j = 0; j < 4; ++j)
                base[(wr * 64 + mi * 16 + fq * 4 + j) * 128 + wc * 64 + ni * 16 + fr] = acc[mi][ni][j];
}

// ---------------- reduce partials ----------------
__global__ void ktv_reduce(const float* __restrict__ part, unsigned short* __restrict__ M2t) {
    int idx = blockIdx.x * 256 + threadIdx.x;
    int bh = idx >> 14, rem = idx & 16383;
    const float* p = part + ((size_t)bh * 8) * 16384 + rem;
    float s = 0.f;
    #pragma unroll
    for (int k = 0; k < 8; ++k) s += p[(size_t)k * 16384];
    M2t[idx] = f2bf(s * 0.08838834764831845f);
}

// ---------------- W2 fold ----------------
__global__ __launch_bounds__(256) void w2_gemm(
    const unsigned short* __restrict__ Wo2, const unsigned short* __restrict__ M2t,
    unsigned short* __restrict__ W2)
{
    const int mt = blockIdx.x;
    const int bh = blockIdx.y;
    const int b = bh >> 4, h = bh & 15;
    const unsigned short* A = Wo2 + (size_t)(mt * 128) * DIMN + h * HD;
    const unsigned short* B = M2t + (size_t)bh * HD * HD;
    unsigned short* Cp = W2 + (size_t)b * DIMN * DIMN + (size_t)(mt * 128) * DIMN + h * HD;
    gemm_tile_core<1, 0>(A, DIMN, B, HD, nullptr, Cp, DIMN, HD);
}

extern "C" void kernel_launch(void* const* d_in, const int* in_sizes, int n_in,
                              void* d_out, int out_size, void* d_ws, size_t ws_size,
                              hipStream_t stream) {
    const float* x    = (const float*)d_in[0];
    const float* fcos = (const float*)d_in[1];
    const float* fsin = (const float*)d_in[2];
    const float* wq   = (const float*)d_in[3];
    const float* bq   = (const float*)d_in[4];
    const float* wk   = (const float*)d_in[5];
    const float* bk   = (const float*)d_in[6];
    const float* wv   = (const float*)d_in[7];
    const float* bv   = (const float*)d_in[8];
    const float* wo   = (const float*)d_in[9];
    const float* bo   = (const float*)d_in[10];
    float* out = (float*)d_out;

    char* ws = (char*)d_ws;
    size_t off = 0;
    auto alloc = [&](size_t bytes) { char* p = ws + off; off += (bytes + 255) & ~(size_t)255; return p; };

    unsigned short* Xb   = (unsigned short*)alloc((size_t)ROWS * DIMN * 2);
    unsigned short* Wcat = (unsigned short*)alloc((size_t)NQKV * DIMN * 2);
    unsigned short* Wo2  = (unsigned short*)alloc((size_t)DIMN * DIMN * 2);
    unsigned short* QKV  = (unsigned short*)alloc((size_t)ROWS * NQKV * 2);
    float*          part = (float*)alloc((size_t)32 * 8 * HD * HD * 4);
    unsigned short* M2t  = (unsigned short*)alloc((size_t)32 * HD * HD * 2);
    unsigned short* W2   = (unsigned short*)alloc((size_t)BSZ * DIMN * DIMN * 2);

    // all converts in one launch
    cvt_all<<<24576, 256, 0, stream>>>(x, wq, wk, wv, wo, Xb, Wcat, Wo2);

    // fused QKV projection + bias + RoPE  (M=4096, N=6144, K=2048): 32x48 = 1536 blocks
    gemm97q<<<1536, 256, 0, stream>>>(
        Xb, DIMN, Wcat, DIMN, bq, bk, bv, fcos, fsin, QKV, NQKV, DIMN);

    // reassociated attention (no softmax): M2t = (K^T V)^T/sqrt(d) per (b,h)
    ktv_kernel<<<dim3(8, 32), 256, 0, stream>>>(QKV, part);
    ktv_reduce<<<(32 * 16384) / 256, 256, 0, stream>>>(part, M2t);

    // fold attention + output projection: W2_b = concat_h(Wo_h @ M2_{b,h})
    w2_gemm<<<dim3(16, 32), 256, 0, stream>>>(Wo2, M2t, W2);

    // out = Q @ W2_b^T + bo  (M=4096, N=2048 per batch, K=2048): 128 blocks (r11 engine)
    gemm256o<<<128, 512, 0, stream>>>(
        QKV, NQKV, W2, DIMN, bo, out, DIMN, DIMN);
}

// Round 15
// 237.508 us; speedup vs baseline: 1.1042x; 1.1042x over previous
//
#include <hip/hip_runtime.h>
#include <hip/hip_bf16.h>

#define DIMN 2048
#define NQKV 6144
#define NH 16
#define HD 128
#define BSZ 2
#define SEQ 2048
#define ROWS (BSZ*SEQ)   // 4096

typedef short short8 __attribute__((ext_vector_type(8)));
typedef float f32x4 __attribute__((ext_vector_type(4)));

__device__ __forceinline__ unsigned short f2bf(float f) {
    __hip_bfloat16 h = __float2bfloat16(f);
    unsigned short u; __builtin_memcpy(&u, &h, 2); return u;
}

__device__ __forceinline__ void gld_lds16(const void* g, void* l) {
    __builtin_amdgcn_global_load_lds(
        (const __attribute__((address_space(1))) void*)g,
        (__attribute__((address_space(3))) void*)l, 16, 0, 0);
}

// ---------------- fused f32 -> bf16 converts ----------------
__global__ void cvt_all(const float* __restrict__ x, const float* __restrict__ wq,
                        const float* __restrict__ wk, const float* __restrict__ wv,
                        const float* __restrict__ wo,
                        unsigned short* __restrict__ Xb, unsigned short* __restrict__ Wcat,
                        unsigned short* __restrict__ Wo2) {
    int bid = blockIdx.x;
    const float* in; unsigned short* out; int base;
    if      (bid <  8192) { in = x;  out = Xb;             base = bid; }
    else if (bid < 12288) { in = wq; out = Wcat;           base = bid - 8192; }
    else if (bid < 16384) { in = wk; out = Wcat + 4194304; base = bid - 12288; }
    else if (bid < 20480) { in = wv; out = Wcat + 8388608; base = bid - 16384; }
    else                  { in = wo; out = Wo2;            base = bid - 20480; }
    int i = (base * 256 + threadIdx.x) * 4;
    float4 v = *(const float4*)(in + i);
    ushort4 o; o.x = f2bf(v.x); o.y = f2bf(v.y); o.z = f2bf(v.z); o.w = f2bf(v.w);
    *(ushort4*)(out + i) = o;
}

// ================= m97-style 128x128 GEMM + swizzle (QKV; r12 verbatim, 145us) =========
// 16x16x32 MFMA; swizzle verified 0-conflict (r12); 3 blocks/CU cover barrier drains.
__global__ __launch_bounds__(256) void gemm97(
    const unsigned short* __restrict__ A, int lda,
    const unsigned short* __restrict__ B, int ldb,
    const float* __restrict__ b0, const float* __restrict__ b1, const float* __restrict__ b2,
    const float* __restrict__ fcos, const float* __restrict__ fsin,
    unsigned short* __restrict__ C, int ldc, int K)
{
    __shared__ __align__(16) unsigned short As[128 * 64];  // 16 KB
    __shared__ __align__(16) unsigned short Bs[128 * 64];  // 16 KB

    const int t  = threadIdx.x;
    const int l  = t & 63;
    const int w  = t >> 6;
    const int wr = w >> 1, wc = w & 1;
    const int fr = l & 15, fq = l >> 4;

    // chunked XCD map: each XCD owns an n-stripe (B panel 3MB -> L2-resident)
    const int xcd = blockIdx.x & 7;
    const int j   = blockIdx.x >> 3;
    const int nt  = xcd * 6 + j % 6;   // 48 n-tiles
    const int mt  = j / 6;             // 32 m-tiles
    const int m0 = mt * 128;
    const int n0 = nt * 128;

    // staging source: pre-swizzled col so LINEAR gld_lds dest holds logical col ^ (row&7)
    const int srow = t >> 3;                         // 0..31
    const int scol = ((t & 7) ^ (srow & 7)) * 8;
    const unsigned short* aS = A + (size_t)(m0 + srow) * lda + scol;
    const unsigned short* bS = B + (size_t)(n0 + srow) * ldb + scol;

    f32x4 acc[4][4] = {};

    for (int k0 = 0; k0 < K; k0 += 64) {
        __syncthreads();   // WAR: previous iteration's reads done
        #pragma unroll
        for (int r = 0; r < 4; ++r) {
            gld_lds16(aS + (size_t)(r * 32) * lda + k0, &As[r * 2048 + t * 8]);
            gld_lds16(bS + (size_t)(r * 32) * ldb + k0, &Bs[r * 2048 + t * 8]);
        }
        __syncthreads();   // compiler drains vmcnt(0) before barrier: data visible
        #pragma unroll
        for (int kk = 0; kk < 2; ++kk) {
            const int co = (((kk << 2) | fq) ^ (fr & 7)) * 8;   // swizzled col offset
            short8 a[4], b[4];
            #pragma unroll
            for (int mi = 0; mi < 4; ++mi)
                a[mi] = *(const short8*)&As[(wr * 64 + mi * 16 + fr) * 64 + co];
            #pragma unroll
            for (int ni = 0; ni < 4; ++ni)
                b[ni] = *(const short8*)&Bs[(wc * 64 + ni * 16 + fr) * 64 + co];
            #pragma unroll
            for (int mi = 0; mi < 4; ++mi)
                #pragma unroll
                for (int ni = 0; ni < 4; ++ni)
                    acc[mi][ni] = __builtin_amdgcn_mfma_f32_16x16x32_bf16(a[mi], b[ni], acc[mi][ni], 0, 0, 0);
        }
    }

    // ---- epilogue: QKV region bias + fused RoPE (cols < 4096), bf16 store
    #pragma unroll
    for (int mi = 0; mi < 4; ++mi) {
        #pragma unroll
        for (int ni = 0; ni < 4; ++ni) {
            #pragma unroll
            for (int j2 = 0; j2 < 4; ++j2) {
                const int r  = m0 + wr * 64 + mi * 16 + fq * 4 + j2;
                const int cg = n0 + wc * 64 + ni * 16 + fr;
                float v = acc[mi][ni][j2];
                v += (cg < 2048) ? b0[cg] : ((cg < 4096) ? b1[cg - 2048] : b2[cg - 4096]);
                if (cg < 4096) {  // block-uniform branch: RoPE on Q and K
                    const int s = r & (SEQ - 1);
                    const int i = (cg >> 1) & 63;
                    const float cs = fcos[s * 64 + i];
                    const float sn = fsin[s * 64 + i];
                    const float p  = __shfl_xor(v, 1);
                    v = (fr & 1) ? (p * sn + v * cs) : (v * cs - p * sn);
                }
                C[(size_t)r * ldc + cg] = f2bf(v);
            }
        }
    }
}

// ================= 256x256 de-convoyed GEMM (out; r13 verbatim, ~32us) ==========
__global__ __launch_bounds__(512, 2) void gemm256o(
    const unsigned short* __restrict__ A, int lda,
    const unsigned short* __restrict__ B, int ldb,
    const float* __restrict__ b0,
    float* __restrict__ C, int ldc, int K)
{
    __shared__ __align__(16) unsigned short As[32768];  // 64 KB: [2buf][2half][128][64]
    __shared__ __align__(16) unsigned short Bs[32768];  // 64 KB

    const int t  = threadIdx.x;
    const int l  = t & 63;
    const int w  = t >> 6;
    const int wr = w >> 2;
    const int wc = w & 3;
    const int fr = l & 15, fq = l >> 4;

    const int xcd = blockIdx.x & 7;
    const int j   = blockIdx.x >> 3;
    const int mt  = (xcd >> 1) * 4 + (j >> 2);
    const int nt  = (xcd & 1) * 4 + (j & 3);
    const int m0 = mt * 256;
    const int n0 = nt * 256;

    const unsigned short* Bsel = B;
    if (m0 >= 2048) Bsel += (size_t)2048 * 2048;  // per-batch W2

    const int srow = t >> 3;
    const int scol = ((t & 7) ^ (srow & 7)) * 8;
    const unsigned short* aS = A    + (size_t)(m0 + srow) * lda + scol;
    const unsigned short* bS = Bsel + (size_t)(n0 + srow) * ldb + scol;

#define STG_A(KT, H) do { \
    const unsigned short* s_ = aS + (size_t)(H) * 128 * lda + (size_t)(KT) * 64; \
    gld_lds16(s_,                    &As[(((KT) & 1) << 14) + ((H) << 13) + t * 8]); \
    gld_lds16(s_ + (size_t)64 * lda, &As[(((KT) & 1) << 14) + ((H) << 13) + 4096 + t * 8]); \
  } while (0)
#define STG_B(KT, H) do { \
    const unsigned short* s_ = bS + (size_t)(H) * 128 * ldb + (size_t)(KT) * 64; \
    gld_lds16(s_,                    &Bs[(((KT) & 1) << 14) + ((H) << 13) + t * 8]); \
    gld_lds16(s_ + (size_t)64 * ldb, &Bs[(((KT) & 1) << 14) + ((H) << 13) + 4096 + t * 8]); \
  } while (0)

    const int cK0 = (fq ^ (fr & 7)) * 8;
    const int cK1 = ((4 + fq) ^ (fr & 7)) * 8;
    const int aB0 = wr * 8192 + fr * 64;
    const int bB0 = wc * 4096 + fr * 64;

    const unsigned aA0 = (unsigned)(size_t)&As[aB0 + cK0];
    const unsigned aA1 = (unsigned)(size_t)&As[aB0 + cK1];
    const unsigned bA0 = (unsigned)(size_t)&Bs[bB0 + cK0];
    const unsigned bA1 = (unsigned)(size_t)&Bs[bB0 + cK1];

    short8 aF[4][2], bF0[2][2], bF1[2][2];
    f32x4  acc[8][4] = {};

#define DSR(dst, areg, OFF) \
    asm volatile("ds_read_b128 %0, %1 offset:%2" : "=v"(dst) : "v"(areg), "n"(OFF))

#define RD_A(DDB, QM) do { \
    DSR(aF[0][0], aA0, (DDB) + (QM) * 8192 + 0);    DSR(aF[0][1], aA1, (DDB) + (QM) * 8192 + 0); \
    DSR(aF[1][0], aA0, (DDB) + (QM) * 8192 + 2048); DSR(aF[1][1], aA1, (DDB) + (QM) * 8192 + 2048); \
    DSR(aF[2][0], aA0, (DDB) + (QM) * 8192 + 4096); DSR(aF[2][1], aA1, (DDB) + (QM) * 8192 + 4096); \
    DSR(aF[3][0], aA0, (DDB) + (QM) * 8192 + 6144); DSR(aF[3][1], aA1, (DDB) + (QM) * 8192 + 6144); \
  } while (0)
#define RD_B(DDB, QN, BF) do { \
    DSR(BF[0][0], bA0, (DDB) + (QN) * 4096 + 0);    DSR(BF[0][1], bA1, (DDB) + (QN) * 4096 + 0); \
    DSR(BF[1][0], bA0, (DDB) + (QN) * 4096 + 2048); DSR(BF[1][1], bA1, (DDB) + (QN) * 4096 + 2048); \
  } while (0)

#define BAR() asm volatile("s_barrier" ::: "memory")

#define MM(QM, QN, BF) do { \
    _Pragma("unroll") for (int m2 = 0; m2 < 4; ++m2) \
      _Pragma("unroll") for (int n2 = 0; n2 < 2; ++n2) { \
        acc[(QM)*4+m2][(QN)*2+n2] = __builtin_amdgcn_mfma_f32_16x16x32_bf16( \
            aF[m2][0], BF[n2][0], acc[(QM)*4+m2][(QN)*2+n2], 0, 0, 0); \
        acc[(QM)*4+m2][(QN)*2+n2] = __builtin_amdgcn_mfma_f32_16x16x32_bf16( \
            aF[m2][1], BF[n2][1], acc[(QM)*4+m2][(QN)*2+n2], 0, 0, 0); } \
  } while (0)

#define TILE(KT, DDB) do { \
    if ((KT) + 1 < ktT) { \
        STG_A((KT) + 1, 0); STG_A((KT) + 1, 1); \
        STG_B((KT) + 1, 0); STG_B((KT) + 1, 1); \
    } \
    RD_A(DDB, 0); RD_B(DDB, 0, bF0); RD_B(DDB, 1, bF1); \
    asm volatile("s_waitcnt lgkmcnt(4)"); \
    __builtin_amdgcn_sched_barrier(0); \
    __builtin_amdgcn_s_setprio(1); \
    MM(0, 0, bF0); \
    asm volatile("s_waitcnt lgkmcnt(0)"); \
    __builtin_amdgcn_sched_barrier(0); \
    MM(0, 1, bF1); \
    __builtin_amdgcn_s_setprio(0); \
    RD_A(DDB, 1); \
    asm volatile("s_waitcnt lgkmcnt(0)"); \
    __builtin_amdgcn_sched_barrier(0); \
    __builtin_amdgcn_s_setprio(1); \
    MM(1, 0, bF0); MM(1, 1, bF1); \
    __builtin_amdgcn_s_setprio(0); \
    asm volatile("s_waitcnt vmcnt(0)"); \
    __builtin_amdgcn_sched_barrier(0); \
    BAR(); \
  } while (0)

    const int ktT = K >> 6;   // 32

    STG_A(0, 0); STG_A(0, 1);
    STG_B(0, 0); STG_B(0, 1);
    asm volatile("s_waitcnt vmcnt(0)");
    __builtin_amdgcn_sched_barrier(0);
    BAR();

    for (int kt = 0; kt < ktT; kt += 2) {
        TILE(kt, 0);
        TILE(kt + 1, 32768);
    }

#undef TILE
#undef MM
#undef BAR
#undef RD_A
#undef RD_B
#undef DSR
#undef STG_A
#undef STG_B

    #pragma unroll
    for (int mi = 0; mi < 8; ++mi) {
        #pragma unroll
        for (int ni = 0; ni < 4; ++ni) {
            #pragma unroll
            for (int j2 = 0; j2 < 4; ++j2) {
                const int r  = m0 + wr * 128 + mi * 16 + fq * 4 + j2;
                const int cg = n0 + wc * 64 + ni * 16 + fr;
                C[(size_t)r * ldc + cg] = acc[mi][ni][j2] + b0[cg];
            }
        }
    }
}

// ---------------- 128x128 GEMM core (small GEMMs) ----------------
template<int OUT_BF16, int HAS_BIAS>
__device__ __forceinline__ void gemm_tile_core(
    const unsigned short* __restrict__ A, int lda,
    const unsigned short* __restrict__ B, int ldb,
    const float* __restrict__ bias,
    void* __restrict__ Cptr, int ldc, int K)
{
    __shared__ __align__(16) unsigned short As[128 * 64];
    __shared__ __align__(16) unsigned short Bs[128 * 64];

    const int t  = threadIdx.x;
    const int l  = t & 63;
    const int w  = t >> 6;
    const int wr = w >> 1, wc = w & 1;
    const int fr = l & 15, fq = l >> 4;

    f32x4 acc[4][4] = {};

    const int srow = t >> 3;
    const int scol = (t & 7) * 8;

    for (int k0 = 0; k0 < K; k0 += 64) {
        __syncthreads();
        #pragma unroll
        for (int r = 0; r < 4; ++r) {
            gld_lds16(A + (size_t)(r * 32 + srow) * lda + k0 + scol, &As[(r * 32 + srow) * 64 + scol]);
            gld_lds16(B + (size_t)(r * 32 + srow) * ldb + k0 + scol, &Bs[(r * 32 + srow) * 64 + scol]);
        }
        __syncthreads();
        #pragma unroll
        for (int kk = 0; kk < 2; ++kk) {
            short8 a[4], b[4];
            #pragma unroll
            for (int mi = 0; mi < 4; ++mi)
                a[mi] = *(const short8*)&As[(wr * 64 + mi * 16 + fr) * 64 + kk * 32 + fq * 8];
            #pragma unroll
            for (int ni = 0; ni < 4; ++ni)
                b[ni] = *(const short8*)&Bs[(wc * 64 + ni * 16 + fr) * 64 + kk * 32 + fq * 8];
            #pragma unroll
            for (int mi = 0; mi < 4; ++mi)
                #pragma unroll
                for (int ni = 0; ni < 4; ++ni)
                    acc[mi][ni] = __builtin_amdgcn_mfma_f32_16x16x32_bf16(a[mi], b[ni], acc[mi][ni], 0, 0, 0);
        }
    }

    #pragma unroll
    for (int mi = 0; mi < 4; ++mi) {
        #pragma unroll
        for (int ni = 0; ni < 4; ++ni) {
            #pragma unroll
            for (int j = 0; j < 4; ++j) {
                int rr = wr * 64 + mi * 16 + fq * 4 + j;
                int cc = wc * 64 + ni * 16 + fr;
                float v = acc[mi][ni][j];
                if (HAS_BIAS) v += bias[cc];
                if (OUT_BF16) ((unsigned short*)Cptr)[(size_t)rr * ldc + cc] = f2bf(v);
                else          ((float*)Cptr)[(size_t)rr * ldc + cc] = v;
            }
        }
    }
}

// ---------------- K^T/V partials ----------------
__global__ __launch_bounds__(256) void ktv_kernel(
    const unsigned short* __restrict__ QKV, float* __restrict__ part)
{
    const int ks = blockIdx.x;
    const int bh = blockIdx.y;
    const int b = bh >> 4, h = bh & 15;
    const unsigned short* Kbase = QKV + (size_t)(b * SEQ + ks * 256) * NQKV + 2048 + h * HD;
    const unsigned short* Vbase = QKV + (size_t)(b * SEQ + ks * 256) * NQKV + 4096 + h * HD;

    __shared__ __align__(16) unsigned short Ks_[64 * 128];
    __shared__ __align__(16) unsigned short Vs_[64 * 128];

    const int t  = threadIdx.x;
    const int l  = t & 63;
    const int w  = t >> 6;
    const int wr = w >> 1, wc = w & 1;
    const int fr = l & 15, fq = l >> 4;

    f32x4 acc[4][4] = {};

    const int srow = t >> 4;
    const int scol = (t & 15) * 8;

    for (int sc = 0; sc < 4; ++sc) {
        __syncthreads();
        #pragma unroll
        for (int r = 0; r < 4; ++r) {
            gld_lds16(Kbase + (size_t)(sc * 64 + r * 16 + srow) * NQKV + scol, &Ks_[(r * 16 + srow) * 128 + scol]);
            gld_lds16(Vbase + (size_t)(sc * 64 + r * 16 + srow) * NQKV + scol, &Vs_[(r * 16 + srow) * 128 + scol]);
        }
        __syncthreads();
        #pragma unroll
        for (int kk = 0; kk < 2; ++kk) {
            short8 a[4], bb[4];
            #pragma unroll
            for (int mi = 0; mi < 4; ++mi)
                #pragma unroll
                for (int i = 0; i < 8; ++i)
                    a[mi][i] = (short)Ks_[(kk * 32 + fq * 8 + i) * 128 + wr * 64 + mi * 16 + fr];
            #pragma unroll
            for (int ni = 0; ni < 4; ++ni)
                #pragma unroll
                for (int i = 0; i < 8; ++i)
                    bb[ni][i] = (short)Vs_[(kk * 32 + fq * 8 + i) * 128 + wc * 64 + ni * 16 + fr];
            #pragma unroll
            for (int mi = 0; mi < 4; ++mi)
                #pragma unroll
                for (int ni = 0; ni < 4; ++ni)
                    acc[mi][ni] = __builtin_amdgcn_mfma_f32_16x16x32_bf16(a[mi], bb[ni], acc[mi][ni], 0, 0, 0);
        }
    }

    float* base = part + ((size_t)bh * 8 + ks) * 16384;
    #pragma unroll
    for (int mi = 0; mi < 4; ++mi)
        #pragma unroll
        for (int ni = 0; ni < 4; ++ni)
            #pragma unroll
            for (int j = 0; j < 4; ++j)
                base[(wr * 64 + mi * 16 + fq * 4 + j) * 128 + wc * 64 + ni * 16 + fr] = acc[mi][ni][j];
}

// ---------------- reduce partials ----------------
__global__ void ktv_reduce(const float* __restrict__ part, unsigned short* __restrict__ M2t) {
    int idx = blockIdx.x * 256 + threadIdx.x;
    int bh = idx >> 14, rem = idx & 16383;
    const float* p = part + ((size_t)bh * 8) * 16384 + rem;
    float s = 0.f;
    #pragma unroll
    for (int k = 0; k < 8; ++k) s += p[(size_t)k * 16384];
    M2t[idx] = f2bf(s * 0.08838834764831845f);
}

// ---------------- W2 fold ----------------
__global__ __launch_bounds__(256) void w2_gemm(
    const unsigned short* __restrict__ Wo2, const unsigned short* __restrict__ M2t,
    unsigned short* __restrict__ W2)
{
    const int mt = blockIdx.x;
    const int bh = blockIdx.y;
    const int b = bh >> 4, h = bh & 15;
    const unsigned short* A = Wo2 + (size_t)(mt * 128) * DIMN + h * HD;
    const unsigned short* B = M2t + (size_t)bh * HD * HD;
    unsigned short* Cp = W2 + (size_t)b * DIMN * DIMN + (size_t)(mt * 128) * DIMN + h * HD;
    gemm_tile_core<1, 0>(A, DIMN, B, HD, nullptr, Cp, DIMN, HD);
}

extern "C" void kernel_launch(void* const* d_in, const int* in_sizes, int n_in,
                              void* d_out, int out_size, void* d_ws, size_t ws_size,
                              hipStream_t stream) {
    const float* x    = (const float*)d_in[0];
    const float* fcos = (const float*)d_in[1];
    const float* fsin = (const float*)d_in[2];
    const float* wq   = (const float*)d_in[3];
    const float* bq   = (const float*)d_in[4];
    const float* wk   = (const float*)d_in[5];
    const float* bk   = (const float*)d_in[6];
    const float* wv   = (const float*)d_in[7];
    const float* bv   = (const float*)d_in[8];
    const float* wo   = (const float*)d_in[9];
    const float* bo   = (const float*)d_in[10];
    float* out = (float*)d_out;

    char* ws = (char*)d_ws;
    size_t off = 0;
    auto alloc = [&](size_t bytes) { char* p = ws + off; off += (bytes + 255) & ~(size_t)255; return p; };

    unsigned short* Xb   = (unsigned short*)alloc((size_t)ROWS * DIMN * 2);
    unsigned short* Wcat = (unsigned short*)alloc((size_t)NQKV * DIMN * 2);
    unsigned short* Wo2  = (unsigned short*)alloc((size_t)DIMN * DIMN * 2);
    unsigned short* QKV  = (unsigned short*)alloc((size_t)ROWS * NQKV * 2);
    float*          part = (float*)alloc((size_t)32 * 8 * HD * HD * 4);
    unsigned short* M2t  = (unsigned short*)alloc((size_t)32 * HD * HD * 2);
    unsigned short* W2   = (unsigned short*)alloc((size_t)BSZ * DIMN * DIMN * 2);

    // all converts in one launch
    cvt_all<<<24576, 256, 0, stream>>>(x, wq, wk, wv, wo, Xb, Wcat, Wo2);

    // fused QKV projection + bias + RoPE  (M=4096, N=6144, K=2048): 1536 blocks
    gemm97<<<1536, 256, 0, stream>>>(
        Xb, DIMN, Wcat, DIMN, bq, bk, bv, fcos, fsin, QKV, NQKV, DIMN);

    // reassociated attention (no softmax): M2t = (K^T V)^T/sqrt(d) per (b,h)
    ktv_kernel<<<dim3(8, 32), 256, 0, stream>>>(QKV, part);
    ktv_reduce<<<(32 * 16384) / 256, 256, 0, stream>>>(part, M2t);

    // fold attention + output projection: W2_b = concat_h(Wo_h @ M2_{b,h})
    w2_gemm<<<dim3(16, 32), 256, 0, stream>>>(Wo2, M2t, W2);

    // out = Q @ W2_b^T + bo  (M=4096, N=2048 per batch, K=2048): 128 blocks
    gemm256o<<<128, 512, 0, stream>>>(
        QKV, NQKV, W2, DIMN, bo, out, DIMN, DIMN);
}

// Round 16
// 214.560 us; speedup vs baseline: 1.2223x; 1.1070x over previous
//
#include <hip/hip_runtime.h>
#include <hip/hip_bf16.h>

#define DIMN 2048
#define NQKV 6144
#define NH 16
#define HD 128
#define BSZ 2
#define SEQ 2048
#define ROWS (BSZ*SEQ)   // 4096

typedef short short8 __attribute__((ext_vector_type(8)));
typedef float f32x4 __attribute__((ext_vector_type(4)));

__device__ __forceinline__ unsigned short f2bf(float f) {
    __hip_bfloat16 h = __float2bfloat16(f);
    unsigned short u; __builtin_memcpy(&u, &h, 2); return u;
}

__device__ __forceinline__ void gld_lds16(const void* g, void* l) {
    __builtin_amdgcn_global_load_lds(
        (const __attribute__((address_space(1))) void*)g,
        (__attribute__((address_space(3))) void*)l, 16, 0, 0);
}

// ---------------- fused f32 -> bf16 converts ----------------
__global__ void cvt_all(const float* __restrict__ x, const float* __restrict__ wq,
                        const float* __restrict__ wk, const float* __restrict__ wv,
                        const float* __restrict__ wo,
                        unsigned short* __restrict__ Xb, unsigned short* __restrict__ Wcat,
                        unsigned short* __restrict__ Wo2) {
    int bid = blockIdx.x;
    const float* in; unsigned short* out; int base;
    if      (bid <  8192) { in = x;  out = Xb;             base = bid; }
    else if (bid < 12288) { in = wq; out = Wcat;           base = bid - 8192; }
    else if (bid < 16384) { in = wk; out = Wcat + 4194304; base = bid - 12288; }
    else if (bid < 20480) { in = wv; out = Wcat + 8388608; base = bid - 16384; }
    else                  { in = wo; out = Wo2;            base = bid - 20480; }
    int i = (base * 256 + threadIdx.x) * 4;
    float4 v = *(const float4*)(in + i);
    ushort4 o; o.x = f2bf(v.x); o.y = f2bf(v.y); o.z = f2bf(v.z); o.w = f2bf(v.w);
    *(ushort4*)(out + i) = o;
}

// ========== 256x256 de-convoyed GEMM (r11-proven engine), 3 epilogue variants ==========
// EPI 0: QK  (256 blocks, N=4096): bf16 out, bias bq|bk + fused RoPE (all cols)
// EPI 1: V   (128 blocks, N=2048): bf16 out, bias bv            (C pre-offset to col 4096)
// EPI 2: out (128 blocks, N=2048): f32 out, bias bo, B(=W2) selected per batch
// Dispatch-width theory: 128-block dispatches measured 1.84x faster per block (r6);
// QK = exactly 1 full round (256 blocks); direct per-GEMM timing lands in top-5.
template<int EPI>
__global__ __launch_bounds__(512, 2) void gemm256d(
    const unsigned short* __restrict__ A, int lda,
    const unsigned short* __restrict__ B, int ldb,
    const float* __restrict__ b0, const float* __restrict__ b1,
    const float* __restrict__ fcos, const float* __restrict__ fsin,
    void* __restrict__ C, int ldc, int K)
{
    __shared__ __align__(16) unsigned short As[32768];  // 64 KB: [2buf][2half][128][64]
    __shared__ __align__(16) unsigned short Bs[32768];  // 64 KB

    const int t  = threadIdx.x;
    const int l  = t & 63;
    const int w  = t >> 6;
    const int wr = w >> 2;
    const int wc = w & 3;
    const int fr = l & 15, fq = l >> 4;

    // L2-chunked XCD maps (B panel 4MB -> L2-resident)
    const int xcd = blockIdx.x & 7;
    const int j   = blockIdx.x >> 3;
    int mt, nt;
    if (EPI == 0) { mt = (xcd & 1) * 8 + (j >> 2); nt = (xcd >> 1) * 4 + (j & 3); }  // 16x16
    else          { mt = (xcd >> 1) * 4 + (j >> 2); nt = (xcd & 1) * 4 + (j & 3); }  // 16x8
    const int m0 = mt * 256;
    const int n0 = nt * 256;

    const unsigned short* Bsel = B;
    if (EPI == 2 && m0 >= 2048) Bsel += (size_t)2048 * 2048;  // per-batch W2

    const int srow = t >> 3;
    const int scol = ((t & 7) ^ (srow & 7)) * 8;
    const unsigned short* aS = A    + (size_t)(m0 + srow) * lda + scol;
    const unsigned short* bS = Bsel + (size_t)(n0 + srow) * ldb + scol;

#define STG_A(KT, H) do { \
    const unsigned short* s_ = aS + (size_t)(H) * 128 * lda + (size_t)(KT) * 64; \
    gld_lds16(s_,                    &As[(((KT) & 1) << 14) + ((H) << 13) + t * 8]); \
    gld_lds16(s_ + (size_t)64 * lda, &As[(((KT) & 1) << 14) + ((H) << 13) + 4096 + t * 8]); \
  } while (0)
#define STG_B(KT, H) do { \
    const unsigned short* s_ = bS + (size_t)(H) * 128 * ldb + (size_t)(KT) * 64; \
    gld_lds16(s_,                    &Bs[(((KT) & 1) << 14) + ((H) << 13) + t * 8]); \
    gld_lds16(s_ + (size_t)64 * ldb, &Bs[(((KT) & 1) << 14) + ((H) << 13) + 4096 + t * 8]); \
  } while (0)

    const int cK0 = (fq ^ (fr & 7)) * 8;
    const int cK1 = ((4 + fq) ^ (fr & 7)) * 8;
    const int aB0 = wr * 8192 + fr * 64;
    const int bB0 = wc * 4096 + fr * 64;

    const unsigned aA0 = (unsigned)(size_t)&As[aB0 + cK0];
    const unsigned aA1 = (unsigned)(size_t)&As[aB0 + cK1];
    const unsigned bA0 = (unsigned)(size_t)&Bs[bB0 + cK0];
    const unsigned bA1 = (unsigned)(size_t)&Bs[bB0 + cK1];

    short8 aF[4][2], bF0[2][2], bF1[2][2];
    f32x4  acc[8][4] = {};

#define DSR(dst, areg, OFF) \
    asm volatile("ds_read_b128 %0, %1 offset:%2" : "=v"(dst) : "v"(areg), "n"(OFF))

#define RD_A(DDB, QM) do { \
    DSR(aF[0][0], aA0, (DDB) + (QM) * 8192 + 0);    DSR(aF[0][1], aA1, (DDB) + (QM) * 8192 + 0); \
    DSR(aF[1][0], aA0, (DDB) + (QM) * 8192 + 2048); DSR(aF[1][1], aA1, (DDB) + (QM) * 8192 + 2048); \
    DSR(aF[2][0], aA0, (DDB) + (QM) * 8192 + 4096); DSR(aF[2][1], aA1, (DDB) + (QM) * 8192 + 4096); \
    DSR(aF[3][0], aA0, (DDB) + (QM) * 8192 + 6144); DSR(aF[3][1], aA1, (DDB) + (QM) * 8192 + 6144); \
  } while (0)
#define RD_B(DDB, QN, BF) do { \
    DSR(BF[0][0], bA0, (DDB) + (QN) * 4096 + 0);    DSR(BF[0][1], bA1, (DDB) + (QN) * 4096 + 0); \
    DSR(BF[1][0], bA0, (DDB) + (QN) * 4096 + 2048); DSR(BF[1][1], bA1, (DDB) + (QN) * 4096 + 2048); \
  } while (0)

#define BAR() asm volatile("s_barrier" ::: "memory")

#define MM(QM, QN, BF) do { \
    _Pragma("unroll") for (int m2 = 0; m2 < 4; ++m2) \
      _Pragma("unroll") for (int n2 = 0; n2 < 2; ++n2) { \
        acc[(QM)*4+m2][(QN)*2+n2] = __builtin_amdgcn_mfma_f32_16x16x32_bf16( \
            aF[m2][0], BF[n2][0], acc[(QM)*4+m2][(QN)*2+n2], 0, 0, 0); \
        acc[(QM)*4+m2][(QN)*2+n2] = __builtin_amdgcn_mfma_f32_16x16x32_bf16( \
            aF[m2][1], BF[n2][1], acc[(QM)*4+m2][(QN)*2+n2], 0, 0, 0); } \
  } while (0)

#define TILE(KT, DDB) do { \
    if ((KT) + 1 < ktT) { \
        STG_A((KT) + 1, 0); STG_A((KT) + 1, 1); \
        STG_B((KT) + 1, 0); STG_B((KT) + 1, 1); \
    } \
    RD_A(DDB, 0); RD_B(DDB, 0, bF0); RD_B(DDB, 1, bF1); \
    asm volatile("s_waitcnt lgkmcnt(4)"); \
    __builtin_amdgcn_sched_barrier(0); \
    __builtin_amdgcn_s_setprio(1); \
    MM(0, 0, bF0); \
    asm volatile("s_waitcnt lgkmcnt(0)"); \
    __builtin_amdgcn_sched_barrier(0); \
    MM(0, 1, bF1); \
    __builtin_amdgcn_s_setprio(0); \
    RD_A(DDB, 1); \
    asm volatile("s_waitcnt lgkmcnt(0)"); \
    __builtin_amdgcn_sched_barrier(0); \
    __builtin_amdgcn_s_setprio(1); \
    MM(1, 0, bF0); MM(1, 1, bF1); \
    __builtin_amdgcn_s_setprio(0); \
    asm volatile("s_waitcnt vmcnt(0)"); \
    __builtin_amdgcn_sched_barrier(0); \
    BAR(); \
  } while (0)

    const int ktT = K >> 6;   // 32

    STG_A(0, 0); STG_A(0, 1);
    STG_B(0, 0); STG_B(0, 1);
    asm volatile("s_waitcnt vmcnt(0)");
    __builtin_amdgcn_sched_barrier(0);
    BAR();

    for (int kt = 0; kt < ktT; kt += 2) {
        TILE(kt, 0);
        TILE(kt + 1, 32768);
    }

#undef TILE
#undef MM
#undef BAR
#undef RD_A
#undef RD_B
#undef DSR
#undef STG_A
#undef STG_B

    // ---- epilogue
    #pragma unroll
    for (int mi = 0; mi < 8; ++mi) {
        #pragma unroll
        for (int ni = 0; ni < 4; ++ni) {
            #pragma unroll
            for (int j2 = 0; j2 < 4; ++j2) {
                const int r  = m0 + wr * 128 + mi * 16 + fq * 4 + j2;
                const int cg = n0 + wc * 64 + ni * 16 + fr;
                float v = acc[mi][ni][j2];
                if (EPI == 0) {
                    v += (cg < 2048) ? b0[cg] : b1[cg - 2048];
                    // RoPE (all cols of QK are rotated)
                    const int s = r & (SEQ - 1);
                    const int i = (cg >> 1) & 63;
                    const float cs = fcos[s * 64 + i];
                    const float sn = fsin[s * 64 + i];
                    const float p  = __shfl_xor(v, 1);
                    v = (fr & 1) ? (p * sn + v * cs) : (v * cs - p * sn);
                    ((unsigned short*)C)[(size_t)r * ldc + cg] = f2bf(v);
                } else if (EPI == 1) {
                    v += b0[cg];
                    ((unsigned short*)C)[(size_t)r * ldc + cg] = f2bf(v);
                } else {
                    v += b0[cg];
                    ((float*)C)[(size_t)r * ldc + cg] = v;
                }
            }
        }
    }
}

// ---------------- 128x128 GEMM core (small GEMMs) ----------------
template<int OUT_BF16, int HAS_BIAS>
__device__ __forceinline__ void gemm_tile_core(
    const unsigned short* __restrict__ A, int lda,
    const unsigned short* __restrict__ B, int ldb,
    const float* __restrict__ bias,
    void* __restrict__ Cptr, int ldc, int K)
{
    __shared__ __align__(16) unsigned short As[128 * 64];
    __shared__ __align__(16) unsigned short Bs[128 * 64];

    const int t  = threadIdx.x;
    const int l  = t & 63;
    const int w  = t >> 6;
    const int wr = w >> 1, wc = w & 1;
    const int fr = l & 15, fq = l >> 4;

    f32x4 acc[4][4] = {};

    const int srow = t >> 3;
    const int scol = (t & 7) * 8;

    for (int k0 = 0; k0 < K; k0 += 64) {
        __syncthreads();
        #pragma unroll
        for (int r = 0; r < 4; ++r) {
            gld_lds16(A + (size_t)(r * 32 + srow) * lda + k0 + scol, &As[(r * 32 + srow) * 64 + scol]);
            gld_lds16(B + (size_t)(r * 32 + srow) * ldb + k0 + scol, &Bs[(r * 32 + srow) * 64 + scol]);
        }
        __syncthreads();
        #pragma unroll
        for (int kk = 0; kk < 2; ++kk) {
            short8 a[4], b[4];
            #pragma unroll
            for (int mi = 0; mi < 4; ++mi)
                a[mi] = *(const short8*)&As[(wr * 64 + mi * 16 + fr) * 64 + kk * 32 + fq * 8];
            #pragma unroll
            for (int ni = 0; ni < 4; ++ni)
                b[ni] = *(const short8*)&Bs[(wc * 64 + ni * 16 + fr) * 64 + kk * 32 + fq * 8];
            #pragma unroll
            for (int mi = 0; mi < 4; ++mi)
                #pragma unroll
                for (int ni = 0; ni < 4; ++ni)
                    acc[mi][ni] = __builtin_amdgcn_mfma_f32_16x16x32_bf16(a[mi], b[ni], acc[mi][ni], 0, 0, 0);
        }
    }

    #pragma unroll
    for (int mi = 0; mi < 4; ++mi) {
        #pragma unroll
        for (int ni = 0; ni < 4; ++ni) {
            #pragma unroll
            for (int j = 0; j < 4; ++j) {
                int rr = wr * 64 + mi * 16 + fq * 4 + j;
                int cc = wc * 64 + ni * 16 + fr;
                float v = acc[mi][ni][j];
                if (HAS_BIAS) v += bias[cc];
                if (OUT_BF16) ((unsigned short*)Cptr)[(size_t)rr * ldc + cc] = f2bf(v);
                else          ((float*)Cptr)[(size_t)rr * ldc + cc] = v;
            }
        }
    }
}

// ---------------- K^T/V partials ----------------
__global__ __launch_bounds__(256) void ktv_kernel(
    const unsigned short* __restrict__ QKV, float* __restrict__ part)
{
    const int ks = blockIdx.x;
    const int bh = blockIdx.y;
    const int b = bh >> 4, h = bh & 15;
    const unsigned short* Kbase = QKV + (size_t)(b * SEQ + ks * 256) * NQKV + 2048 + h * HD;
    const unsigned short* Vbase = QKV + (size_t)(b * SEQ + ks * 256) * NQKV + 4096 + h * HD;

    __shared__ __align__(16) unsigned short Ks_[64 * 128];
    __shared__ __align__(16) unsigned short Vs_[64 * 128];

    const int t  = threadIdx.x;
    const int l  = t & 63;
    const int w  = t >> 6;
    const int wr = w >> 1, wc = w & 1;
    const int fr = l & 15, fq = l >> 4;

    f32x4 acc[4][4] = {};

    const int srow = t >> 4;
    const int scol = (t & 15) * 8;

    for (int sc = 0; sc < 4; ++sc) {
        __syncthreads();
        #pragma unroll
        for (int r = 0; r < 4; ++r) {
            gld_lds16(Kbase + (size_t)(sc * 64 + r * 16 + srow) * NQKV + scol, &Ks_[(r * 16 + srow) * 128 + scol]);
            gld_lds16(Vbase + (size_t)(sc * 64 + r * 16 + srow) * NQKV + scol, &Vs_[(r * 16 + srow) * 128 + scol]);
        }
        __syncthreads();
        #pragma unroll
        for (int kk = 0; kk < 2; ++kk) {
            short8 a[4], bb[4];
            #pragma unroll
            for (int mi = 0; mi < 4; ++mi)
                #pragma unroll
                for (int i = 0; i < 8; ++i)
                    a[mi][i] = (short)Ks_[(kk * 32 + fq * 8 + i) * 128 + wr * 64 + mi * 16 + fr];
            #pragma unroll
            for (int ni = 0; ni < 4; ++ni)
                #pragma unroll
                for (int i = 0; i < 8; ++i)
                    bb[ni][i] = (short)Vs_[(kk * 32 + fq * 8 + i) * 128 + wc * 64 + ni * 16 + fr];
            #pragma unroll
            for (int mi = 0; mi < 4; ++mi)
                #pragma unroll
                for (int ni = 0; ni < 4; ++ni)
                    acc[mi][ni] = __builtin_amdgcn_mfma_f32_16x16x32_bf16(a[mi], bb[ni], acc[mi][ni], 0, 0, 0);
        }
    }

    float* base = part + ((size_t)bh * 8 + ks) * 16384;
    #pragma unroll
    for (int mi = 0; mi < 4; ++mi)
        #pragma unroll
        for (int ni = 0; ni < 4; ++ni)
            #pragma unroll
            for (int j = 0; j < 4; ++j)
                base[(wr * 64 + mi * 16 + fq * 4 + j) * 128 + wc * 64 + ni * 16 + fr] = acc[mi][ni][j];
}

// ---------------- reduce partials ----------------
__global__ void ktv_reduce(const float* __restrict__ part, unsigned short* __restrict__ M2t) {
    int idx = blockIdx.x * 256 + threadIdx.x;
    int bh = idx >> 14, rem = idx & 16383;
    const float* p = part + ((size_t)bh * 8) * 16384 + rem;
    float s = 0.f;
    #pragma unroll
    for (int k = 0; k < 8; ++k) s += p[(size_t)k * 16384];
    M2t[idx] = f2bf(s * 0.08838834764831845f);
}

// ---------------- W2 fold ----------------
__global__ __launch_bounds__(256) void w2_gemm(
    const unsigned short* __restrict__ Wo2, const unsigned short* __restrict__ M2t,
    unsigned short* __restrict__ W2)
{
    const int mt = blockIdx.x;
    const int bh = blockIdx.y;
    const int b = bh >> 4, h = bh & 15;
    const unsigned short* A = Wo2 + (size_t)(mt * 128) * DIMN + h * HD;
    const unsigned short* B = M2t + (size_t)bh * HD * HD;
    unsigned short* Cp = W2 + (size_t)b * DIMN * DIMN + (size_t)(mt * 128) * DIMN + h * HD;
    gemm_tile_core<1, 0>(A, DIMN, B, HD, nullptr, Cp, DIMN, HD);
}

extern "C" void kernel_launch(void* const* d_in, const int* in_sizes, int n_in,
                              void* d_out, int out_size, void* d_ws, size_t ws_size,
                              hipStream_t stream) {
    const float* x    = (const float*)d_in[0];
    const float* fcos = (const float*)d_in[1];
    const float* fsin = (const float*)d_in[2];
    const float* wq   = (const float*)d_in[3];
    const float* bq   = (const float*)d_in[4];
    const float* wk   = (const float*)d_in[5];
    const float* bk   = (const float*)d_in[6];
    const float* wv   = (const float*)d_in[7];
    const float* bv   = (const float*)d_in[8];
    const float* wo   = (const float*)d_in[9];
    const float* bo   = (const float*)d_in[10];
    float* out = (float*)d_out;

    char* ws = (char*)d_ws;
    size_t off = 0;
    auto alloc = [&](size_t bytes) { char* p = ws + off; off += (bytes + 255) & ~(size_t)255; return p; };

    unsigned short* Xb   = (unsigned short*)alloc((size_t)ROWS * DIMN * 2);
    unsigned short* Wcat = (unsigned short*)alloc((size_t)NQKV * DIMN * 2);
    unsigned short* Wo2  = (unsigned short*)alloc((size_t)DIMN * DIMN * 2);
    unsigned short* QKV  = (unsigned short*)alloc((size_t)ROWS * NQKV * 2);
    float*          part = (float*)alloc((size_t)32 * 8 * HD * HD * 4);
    unsigned short* M2t  = (unsigned short*)alloc((size_t)32 * HD * HD * 2);
    unsigned short* W2   = (unsigned short*)alloc((size_t)BSZ * DIMN * DIMN * 2);

    // all converts in one launch
    cvt_all<<<24576, 256, 0, stream>>>(x, wq, wk, wv, wo, Xb, Wcat, Wo2);

    // QK projection + bias + RoPE  (M=4096, N=4096, K=2048): 256 blocks = 1 exact round
    gemm256d<0><<<256, 512, 0, stream>>>(
        Xb, DIMN, Wcat, DIMN, bq, bk, fcos, fsin, QKV, NQKV, DIMN);

    // V projection + bias  (M=4096, N=2048, K=2048): 128 blocks (fast dispatch regime)
    gemm256d<1><<<128, 512, 0, stream>>>(
        Xb, DIMN, Wcat + (size_t)4096 * DIMN, DIMN, bv, nullptr, nullptr, nullptr,
        QKV + 4096, NQKV, DIMN);

    // reassociated attention (no softmax): M2t = (K^T V)^T/sqrt(d) per (b,h)
    ktv_kernel<<<dim3(8, 32), 256, 0, stream>>>(QKV, part);
    ktv_reduce<<<(32 * 16384) / 256, 256, 0, stream>>>(part, M2t);

    // fold attention + output projection: W2_b = concat_h(Wo_h @ M2_{b,h})
    w2_gemm<<<dim3(16, 32), 256, 0, stream>>>(Wo2, M2t, W2);

    // out = Q @ W2_b^T + bo  (M=4096, N=2048 per batch, K=2048): 128 blocks
    gemm256d<2><<<128, 512, 0, stream>>>(
        QKV, NQKV, W2, DIMN, bo, nullptr, nullptr, nullptr, out, DIMN, DIMN);
}

// Round 17
// 200.314 us; speedup vs baseline: 1.3093x; 1.0711x over previous
//
#include <hip/hip_runtime.h>
#include <hip/hip_bf16.h>

#define DIMN 2048
#define NQKV 6144
#define NH 16
#define HD 128
#define BSZ 2
#define SEQ 2048
#define ROWS (BSZ*SEQ)   // 4096

typedef short short8 __attribute__((ext_vector_type(8)));
typedef float f32x4 __attribute__((ext_vector_type(4)));

__device__ __forceinline__ unsigned short f2bf(float f) {
    __hip_bfloat16 h = __float2bfloat16(f);
    unsigned short u; __builtin_memcpy(&u, &h, 2); return u;
}

__device__ __forceinline__ void gld_lds16(const void* g, void* l) {
    __builtin_amdgcn_global_load_lds(
        (const __attribute__((address_space(1))) void*)g,
        (__attribute__((address_space(3))) void*)l, 16, 0, 0);
}

// ---------------- fused f32 -> bf16 converts ----------------
__global__ void cvt_all(const float* __restrict__ x, const float* __restrict__ wq,
                        const float* __restrict__ wk, const float* __restrict__ wv,
                        const float* __restrict__ wo,
                        unsigned short* __restrict__ Xb, unsigned short* __restrict__ Wcat,
                        unsigned short* __restrict__ Wo2) {
    int bid = blockIdx.x;
    const float* in; unsigned short* out; int base;
    if      (bid <  8192) { in = x;  out = Xb;             base = bid; }
    else if (bid < 12288) { in = wq; out = Wcat;           base = bid - 8192; }
    else if (bid < 16384) { in = wk; out = Wcat + 4194304; base = bid - 12288; }
    else if (bid < 20480) { in = wv; out = Wcat + 8388608; base = bid - 16384; }
    else                  { in = wo; out = Wo2;            base = bid - 20480; }
    int i = (base * 256 + threadIdx.x) * 4;
    float4 v = *(const float4*)(in + i);
    ushort4 o; o.x = f2bf(v.x); o.y = f2bf(v.y); o.z = f2bf(v.z); o.w = f2bf(v.w);
    *(ushort4*)(out + i) = o;
}

// ========== 256x256 de-convoyed GEMM (r11-proven engine): QK + out ==========
// EPI 0: QK  (256 blocks, N=4096): bf16 out, bias bq|bk + fused RoPE (all cols)
// EPI 2: out (128 blocks, N=2048): f32 out, bias bo, B(=W2) selected per batch
template<int EPI>
__global__ __launch_bounds__(512, 2) void gemm256d(
    const unsigned short* __restrict__ A, int lda,
    const unsigned short* __restrict__ B, int ldb,
    const float* __restrict__ b0, const float* __restrict__ b1,
    const float* __restrict__ fcos, const float* __restrict__ fsin,
    void* __restrict__ C, int ldc, int K)
{
    __shared__ __align__(16) unsigned short As[32768];  // 64 KB: [2buf][2half][128][64]
    __shared__ __align__(16) unsigned short Bs[32768];  // 64 KB

    const int t  = threadIdx.x;
    const int l  = t & 63;
    const int w  = t >> 6;
    const int wr = w >> 2;
    const int wc = w & 3;
    const int fr = l & 15, fq = l >> 4;

    const int xcd = blockIdx.x & 7;
    const int j   = blockIdx.x >> 3;
    int mt, nt;
    if (EPI == 0) { mt = (xcd & 1) * 8 + (j >> 2); nt = (xcd >> 1) * 4 + (j & 3); }  // 16x16
    else          { mt = (xcd >> 1) * 4 + (j >> 2); nt = (xcd & 1) * 4 + (j & 3); }  // 16x8
    const int m0 = mt * 256;
    const int n0 = nt * 256;

    const unsigned short* Bsel = B;
    if (EPI == 2 && m0 >= 2048) Bsel += (size_t)2048 * 2048;  // per-batch W2

    const int srow = t >> 3;
    const int scol = ((t & 7) ^ (srow & 7)) * 8;
    const unsigned short* aS = A    + (size_t)(m0 + srow) * lda + scol;
    const unsigned short* bS = Bsel + (size_t)(n0 + srow) * ldb + scol;

#define STG_A(KT, H) do { \
    const unsigned short* s_ = aS + (size_t)(H) * 128 * lda + (size_t)(KT) * 64; \
    gld_lds16(s_,                    &As[(((KT) & 1) << 14) + ((H) << 13) + t * 8]); \
    gld_lds16(s_ + (size_t)64 * lda, &As[(((KT) & 1) << 14) + ((H) << 13) + 4096 + t * 8]); \
  } while (0)
#define STG_B(KT, H) do { \
    const unsigned short* s_ = bS + (size_t)(H) * 128 * ldb + (size_t)(KT) * 64; \
    gld_lds16(s_,                    &Bs[(((KT) & 1) << 14) + ((H) << 13) + t * 8]); \
    gld_lds16(s_ + (size_t)64 * ldb, &Bs[(((KT) & 1) << 14) + ((H) << 13) + 4096 + t * 8]); \
  } while (0)

    const int cK0 = (fq ^ (fr & 7)) * 8;
    const int cK1 = ((4 + fq) ^ (fr & 7)) * 8;
    const int aB0 = wr * 8192 + fr * 64;
    const int bB0 = wc * 4096 + fr * 64;

    const unsigned aA0 = (unsigned)(size_t)&As[aB0 + cK0];
    const unsigned aA1 = (unsigned)(size_t)&As[aB0 + cK1];
    const unsigned bA0 = (unsigned)(size_t)&Bs[bB0 + cK0];
    const unsigned bA1 = (unsigned)(size_t)&Bs[bB0 + cK1];

    short8 aF[4][2], bF0[2][2], bF1[2][2];
    f32x4  acc[8][4] = {};

#define DSR(dst, areg, OFF) \
    asm volatile("ds_read_b128 %0, %1 offset:%2" : "=v"(dst) : "v"(areg), "n"(OFF))

#define RD_A(DDB, QM) do { \
    DSR(aF[0][0], aA0, (DDB) + (QM) * 8192 + 0);    DSR(aF[0][1], aA1, (DDB) + (QM) * 8192 + 0); \
    DSR(aF[1][0], aA0, (DDB) + (QM) * 8192 + 2048); DSR(aF[1][1], aA1, (DDB) + (QM) * 8192 + 2048); \
    DSR(aF[2][0], aA0, (DDB) + (QM) * 8192 + 4096); DSR(aF[2][1], aA1, (DDB) + (QM) * 8192 + 4096); \
    DSR(aF[3][0], aA0, (DDB) + (QM) * 8192 + 6144); DSR(aF[3][1], aA1, (DDB) + (QM) * 8192 + 6144); \
  } while (0)
#define RD_B(DDB, QN, BF) do { \
    DSR(BF[0][0], bA0, (DDB) + (QN) * 4096 + 0);    DSR(BF[0][1], bA1, (DDB) + (QN) * 4096 + 0); \
    DSR(BF[1][0], bA0, (DDB) + (QN) * 4096 + 2048); DSR(BF[1][1], bA1, (DDB) + (QN) * 4096 + 2048); \
  } while (0)

#define BAR() asm volatile("s_barrier" ::: "memory")

#define MM(QM, QN, BF) do { \
    _Pragma("unroll") for (int m2 = 0; m2 < 4; ++m2) \
      _Pragma("unroll") for (int n2 = 0; n2 < 2; ++n2) { \
        acc[(QM)*4+m2][(QN)*2+n2] = __builtin_amdgcn_mfma_f32_16x16x32_bf16( \
            aF[m2][0], BF[n2][0], acc[(QM)*4+m2][(QN)*2+n2], 0, 0, 0); \
        acc[(QM)*4+m2][(QN)*2+n2] = __builtin_amdgcn_mfma_f32_16x16x32_bf16( \
            aF[m2][1], BF[n2][1], acc[(QM)*4+m2][(QN)*2+n2], 0, 0, 0); } \
  } while (0)

#define TILE(KT, DDB) do { \
    if ((KT) + 1 < ktT) { \
        STG_A((KT) + 1, 0); STG_A((KT) + 1, 1); \
        STG_B((KT) + 1, 0); STG_B((KT) + 1, 1); \
    } \
    RD_A(DDB, 0); RD_B(DDB, 0, bF0); RD_B(DDB, 1, bF1); \
    asm volatile("s_waitcnt lgkmcnt(4)"); \
    __builtin_amdgcn_sched_barrier(0); \
    __builtin_amdgcn_s_setprio(1); \
    MM(0, 0, bF0); \
    asm volatile("s_waitcnt lgkmcnt(0)"); \
    __builtin_amdgcn_sched_barrier(0); \
    MM(0, 1, bF1); \
    __builtin_amdgcn_s_setprio(0); \
    RD_A(DDB, 1); \
    asm volatile("s_waitcnt lgkmcnt(0)"); \
    __builtin_amdgcn_sched_barrier(0); \
    __builtin_amdgcn_s_setprio(1); \
    MM(1, 0, bF0); MM(1, 1, bF1); \
    __builtin_amdgcn_s_setprio(0); \
    asm volatile("s_waitcnt vmcnt(0)"); \
    __builtin_amdgcn_sched_barrier(0); \
    BAR(); \
  } while (0)

    const int ktT = K >> 6;   // 32

    STG_A(0, 0); STG_A(0, 1);
    STG_B(0, 0); STG_B(0, 1);
    asm volatile("s_waitcnt vmcnt(0)");
    __builtin_amdgcn_sched_barrier(0);
    BAR();

    for (int kt = 0; kt < ktT; kt += 2) {
        TILE(kt, 0);
        TILE(kt + 1, 32768);
    }

#undef TILE
#undef MM
#undef BAR
#undef RD_A
#undef RD_B
#undef DSR
#undef STG_A
#undef STG_B

    // ---- epilogue
    #pragma unroll
    for (int mi = 0; mi < 8; ++mi) {
        #pragma unroll
        for (int ni = 0; ni < 4; ++ni) {
            #pragma unroll
            for (int j2 = 0; j2 < 4; ++j2) {
                const int r  = m0 + wr * 128 + mi * 16 + fq * 4 + j2;
                const int cg = n0 + wc * 64 + ni * 16 + fr;
                float v = acc[mi][ni][j2];
                if (EPI == 0) {
                    v += (cg < 2048) ? b0[cg] : b1[cg - 2048];
                    const int s = r & (SEQ - 1);
                    const int i = (cg >> 1) & 63;
                    const float cs = fcos[s * 64 + i];
                    const float sn = fsin[s * 64 + i];
                    const float p  = __shfl_xor(v, 1);
                    v = (fr & 1) ? (p * sn + v * cs) : (v * cs - p * sn);
                    ((unsigned short*)C)[(size_t)r * ldc + cg] = f2bf(v);
                } else {
                    v += b0[cg];
                    ((float*)C)[(size_t)r * ldc + cg] = v;
                }
            }
        }
    }
}

// ========== A/B EXPERIMENT: V projection on BM=256 x BN=128, 256 blocks ==========
// Same de-convoyed TILE skeleton; half per-block work; full-machine dispatch.
// acc[8][2]=64 AGPR (no spill), LDS 96 KB, 20 ds_read + 32 MFMA per K-tile.
// Map: 4mt x 8nt chunk per XCD (A panel 4MB, B panel 2MB -> L2-fit).
__global__ __launch_bounds__(512, 2) void gemm_v(
    const unsigned short* __restrict__ A, int lda,
    const unsigned short* __restrict__ B, int ldb,
    const float* __restrict__ bias,
    unsigned short* __restrict__ C, int ldc, int K)
{
    __shared__ __align__(16) unsigned short As[32768];  // 64 KB: [2buf][2half][128][64]
    __shared__ __align__(16) unsigned short Bs[16384];  // 32 KB: [2buf][128][64]

    const int t  = threadIdx.x;
    const int l  = t & 63;
    const int w  = t >> 6;
    const int wr = w >> 2;          // 0..1 (128-row half)
    const int wc = w & 3;           // 0..3 (32-col quarter)
    const int fr = l & 15, fq = l >> 4;

    const int xcd = blockIdx.x & 7;
    const int j   = blockIdx.x >> 3;          // 0..31
    const int mt  = (xcd & 3) * 4 + (j >> 3); // 0..15
    const int nt  = (xcd >> 2) * 8 + (j & 7); // 0..15
    const int m0 = mt * 256;
    const int n0 = nt * 128;

    const int srow = t >> 3;
    const int scol = ((t & 7) ^ (srow & 7)) * 8;
    const unsigned short* aS = A + (size_t)(m0 + srow) * lda + scol;
    const unsigned short* bS = B + (size_t)(n0 + srow) * ldb + scol;

#define VSTG_A(KT, H) do { \
    const unsigned short* s_ = aS + (size_t)(H) * 128 * lda + (size_t)(KT) * 64; \
    gld_lds16(s_,                    &As[(((KT) & 1) << 14) + ((H) << 13) + t * 8]); \
    gld_lds16(s_ + (size_t)64 * lda, &As[(((KT) & 1) << 14) + ((H) << 13) + 4096 + t * 8]); \
  } while (0)
#define VSTG_B(KT) do { \
    const unsigned short* s_ = bS + (size_t)(KT) * 64; \
    gld_lds16(s_,                    &Bs[(((KT) & 1) << 13) + t * 8]); \
    gld_lds16(s_ + (size_t)64 * ldb, &Bs[(((KT) & 1) << 13) + 4096 + t * 8]); \
  } while (0)

    const int cK0 = (fq ^ (fr & 7)) * 8;
    const int cK1 = ((4 + fq) ^ (fr & 7)) * 8;
    const int aB0 = wr * 8192 + fr * 64;   // elements (A half = wr)
    const int bB0 = wc * 2048 + fr * 64;   // elements (wc*32 rows)

    const unsigned aA0 = (unsigned)(size_t)&As[aB0 + cK0];
    const unsigned aA1 = (unsigned)(size_t)&As[aB0 + cK1];
    const unsigned bA0 = (unsigned)(size_t)&Bs[bB0 + cK0];
    const unsigned bA1 = (unsigned)(size_t)&Bs[bB0 + cK1];

    short8 aF[4][2], bF0[2], bF1[2];
    f32x4  acc[8][2] = {};

#define VDSR(dst, areg, OFF) \
    asm volatile("ds_read_b128 %0, %1 offset:%2" : "=v"(dst) : "v"(areg), "n"(OFF))

#define VRD_A(DA, QM) do { \
    VDSR(aF[0][0], aA0, (DA) + (QM) * 8192 + 0);    VDSR(aF[0][1], aA1, (DA) + (QM) * 8192 + 0); \
    VDSR(aF[1][0], aA0, (DA) + (QM) * 8192 + 2048); VDSR(aF[1][1], aA1, (DA) + (QM) * 8192 + 2048); \
    VDSR(aF[2][0], aA0, (DA) + (QM) * 8192 + 4096); VDSR(aF[2][1], aA1, (DA) + (QM) * 8192 + 4096); \
    VDSR(aF[3][0], aA0, (DA) + (QM) * 8192 + 6144); VDSR(aF[3][1], aA1, (DA) + (QM) * 8192 + 6144); \
  } while (0)
#define VRD_B(DB, NI, BF) do { \
    VDSR(BF[0], bA0, (DB) + (NI) * 2048); VDSR(BF[1], bA1, (DB) + (NI) * 2048); \
  } while (0)

#define VBAR() asm volatile("s_barrier" ::: "memory")

#define VMM(QM, NI, BF) do { \
    _Pragma("unroll") for (int m2 = 0; m2 < 4; ++m2) { \
        acc[(QM)*4+m2][NI] = __builtin_amdgcn_mfma_f32_16x16x32_bf16( \
            aF[m2][0], BF[0], acc[(QM)*4+m2][NI], 0, 0, 0); \
        acc[(QM)*4+m2][NI] = __builtin_amdgcn_mfma_f32_16x16x32_bf16( \
            aF[m2][1], BF[1], acc[(QM)*4+m2][NI], 0, 0, 0); } \
  } while (0)

#define VTILE(KT, DA, DB) do { \
    if ((KT) + 1 < ktT) { \
        VSTG_A((KT) + 1, 0); VSTG_A((KT) + 1, 1); VSTG_B((KT) + 1); \
    } \
    VRD_A(DA, 0); VRD_B(DB, 0, bF0); VRD_B(DB, 1, bF1); \
    asm volatile("s_waitcnt lgkmcnt(2)"); \
    __builtin_amdgcn_sched_barrier(0); \
    __builtin_amdgcn_s_setprio(1); \
    VMM(0, 0, bF0); \
    asm volatile("s_waitcnt lgkmcnt(0)"); \
    __builtin_amdgcn_sched_barrier(0); \
    VMM(0, 1, bF1); \
    __builtin_amdgcn_s_setprio(0); \
    VRD_A(DA, 1); \
    asm volatile("s_waitcnt lgkmcnt(0)"); \
    __builtin_amdgcn_sched_barrier(0); \
    __builtin_amdgcn_s_setprio(1); \
    VMM(1, 0, bF0); VMM(1, 1, bF1); \
    __builtin_amdgcn_s_setprio(0); \
    asm volatile("s_waitcnt vmcnt(0)"); \
    __builtin_amdgcn_sched_barrier(0); \
    VBAR(); \
  } while (0)

    const int ktT = K >> 6;   // 32

    VSTG_A(0, 0); VSTG_A(0, 1); VSTG_B(0);
    asm volatile("s_waitcnt vmcnt(0)");
    __builtin_amdgcn_sched_barrier(0);
    VBAR();

    for (int kt = 0; kt < ktT; kt += 2) {
        VTILE(kt, 0, 0);
        VTILE(kt + 1, 32768, 16384);
    }

#undef VTILE
#undef VMM
#undef VBAR
#undef VRD_A
#undef VRD_B
#undef VDSR
#undef VSTG_A
#undef VSTG_B

    // ---- epilogue: bias, bf16 store
    #pragma unroll
    for (int mi = 0; mi < 8; ++mi) {
        #pragma unroll
        for (int ni = 0; ni < 2; ++ni) {
            #pragma unroll
            for (int j2 = 0; j2 < 4; ++j2) {
                const int r  = m0 + wr * 128 + mi * 16 + fq * 4 + j2;
                const int cg = n0 + wc * 32 + ni * 16 + fr;
                C[(size_t)r * ldc + cg] = f2bf(acc[mi][ni][j2] + bias[cg]);
            }
        }
    }
}

// ---------------- 128x128 GEMM core (small GEMMs) ----------------
template<int OUT_BF16, int HAS_BIAS>
__device__ __forceinline__ void gemm_tile_core(
    const unsigned short* __restrict__ A, int lda,
    const unsigned short* __restrict__ B, int ldb,
    const float* __restrict__ bias,
    void* __restrict__ Cptr, int ldc, int K)
{
    __shared__ __align__(16) unsigned short As[128 * 64];
    __shared__ __align__(16) unsigned short Bs[128 * 64];

    const int t  = threadIdx.x;
    const int l  = t & 63;
    const int w  = t >> 6;
    const int wr = w >> 1, wc = w & 1;
    const int fr = l & 15, fq = l >> 4;

    f32x4 acc[4][4] = {};

    const int srow = t >> 3;
    const int scol = (t & 7) * 8;

    for (int k0 = 0; k0 < K; k0 += 64) {
        __syncthreads();
        #pragma unroll
        for (int r = 0; r < 4; ++r) {
            gld_lds16(A + (size_t)(r * 32 + srow) * lda + k0 + scol, &As[(r * 32 + srow) * 64 + scol]);
            gld_lds16(B + (size_t)(r * 32 + srow) * ldb + k0 + scol, &Bs[(r * 32 + srow) * 64 + scol]);
        }
        __syncthreads();
        #pragma unroll
        for (int kk = 0; kk < 2; ++kk) {
            short8 a[4], b[4];
            #pragma unroll
            for (int mi = 0; mi < 4; ++mi)
                a[mi] = *(const short8*)&As[(wr * 64 + mi * 16 + fr) * 64 + kk * 32 + fq * 8];
            #pragma unroll
            for (int ni = 0; ni < 4; ++ni)
                b[ni] = *(const short8*)&Bs[(wc * 64 + ni * 16 + fr) * 64 + kk * 32 + fq * 8];
            #pragma unroll
            for (int mi = 0; mi < 4; ++mi)
                #pragma unroll
                for (int ni = 0; ni < 4; ++ni)
                    acc[mi][ni] = __builtin_amdgcn_mfma_f32_16x16x32_bf16(a[mi], b[ni], acc[mi][ni], 0, 0, 0);
        }
    }

    #pragma unroll
    for (int mi = 0; mi < 4; ++mi) {
        #pragma unroll
        for (int ni = 0; ni < 4; ++ni) {
            #pragma unroll
            for (int j = 0; j < 4; ++j) {
                int rr = wr * 64 + mi * 16 + fq * 4 + j;
                int cc = wc * 64 + ni * 16 + fr;
                float v = acc[mi][ni][j];
                if (HAS_BIAS) v += bias[cc];
                if (OUT_BF16) ((unsigned short*)Cptr)[(size_t)rr * ldc + cc] = f2bf(v);
                else          ((float*)Cptr)[(size_t)rr * ldc + cc] = v;
            }
        }
    }
}

// ---------------- K^T/V partials ----------------
__global__ __launch_bounds__(256) void ktv_kernel(
    const unsigned short* __restrict__ QKV, float* __restrict__ part)
{
    const int ks = blockIdx.x;
    const int bh = blockIdx.y;
    const int b = bh >> 4, h = bh & 15;
    const unsigned short* Kbase = QKV + (size_t)(b * SEQ + ks * 256) * NQKV + 2048 + h * HD;
    const unsigned short* Vbase = QKV + (size_t)(b * SEQ + ks * 256) * NQKV + 4096 + h * HD;

    __shared__ __align__(16) unsigned short Ks_[64 * 128];
    __shared__ __align__(16) unsigned short Vs_[64 * 128];

    const int t  = threadIdx.x;
    const int l  = t & 63;
    const int w  = t >> 6;
    const int wr = w >> 1, wc = w & 1;
    const int fr = l & 15, fq = l >> 4;

    f32x4 acc[4][4] = {};

    const int srow = t >> 4;
    const int scol = (t & 15) * 8;

    for (int sc = 0; sc < 4; ++sc) {
        __syncthreads();
        #pragma unroll
        for (int r = 0; r < 4; ++r) {
            gld_lds16(Kbase + (size_t)(sc * 64 + r * 16 + srow) * NQKV + scol, &Ks_[(r * 16 + srow) * 128 + scol]);
            gld_lds16(Vbase + (size_t)(sc * 64 + r * 16 + srow) * NQKV + scol, &Vs_[(r * 16 + srow) * 128 + scol]);
        }
        __syncthreads();
        #pragma unroll
        for (int kk = 0; kk < 2; ++kk) {
            short8 a[4], bb[4];
            #pragma unroll
            for (int mi = 0; mi < 4; ++mi)
                #pragma unroll
                for (int i = 0; i < 8; ++i)
                    a[mi][i] = (short)Ks_[(kk * 32 + fq * 8 + i) * 128 + wr * 64 + mi * 16 + fr];
            #pragma unroll
            for (int ni = 0; ni < 4; ++ni)
                #pragma unroll
                for (int i = 0; i < 8; ++i)
                    bb[ni][i] = (short)Vs_[(kk * 32 + fq * 8 + i) * 128 + wc * 64 + ni * 16 + fr];
            #pragma unroll
            for (int mi = 0; mi < 4; ++mi)
                #pragma unroll
                for (int ni = 0; ni < 4; ++ni)
                    acc[mi][ni] = __builtin_amdgcn_mfma_f32_16x16x32_bf16(a[mi], bb[ni], acc[mi][ni], 0, 0, 0);
        }
    }

    float* base = part + ((size_t)bh * 8 + ks) * 16384;
    #pragma unroll
    for (int mi = 0; mi < 4; ++mi)
        #pragma unroll
        for (int ni = 0; ni < 4; ++ni)
            #pragma unroll
            for (int j = 0; j < 4; ++j)
                base[(wr * 64 + mi * 16 + fq * 4 + j) * 128 + wc * 64 + ni * 16 + fr] = acc[mi][ni][j];
}

// ---------------- reduce partials ----------------
__global__ void ktv_reduce(const float* __restrict__ part, unsigned short* __restrict__ M2t) {
    int idx = blockIdx.x * 256 + threadIdx.x;
    int bh = idx >> 14, rem = idx & 16383;
    const float* p = part + ((size_t)bh * 8) * 16384 + rem;
    float s = 0.f;
    #pragma unroll
    for (int k = 0; k < 8; ++k) s += p[(size_t)k * 16384];
    M2t[idx] = f2bf(s * 0.08838834764831845f);
}

// ---------------- W2 fold ----------------
__global__ __launch_bounds__(256) void w2_gemm(
    const unsigned short* __restrict__ Wo2, const unsigned short* __restrict__ M2t,
    unsigned short* __restrict__ W2)
{
    const int mt = blockIdx.x;
    const int bh = blockIdx.y;
    const int b = bh >> 4, h = bh & 15;
    const unsigned short* A = Wo2 + (size_t)(mt * 128) * DIMN + h * HD;
    const unsigned short* B = M2t + (size_t)bh * HD * HD;
    unsigned short* Cp = W2 + (size_t)b * DIMN * DIMN + (size_t)(mt * 128) * DIMN + h * HD;
    gemm_tile_core<1, 0>(A, DIMN, B, HD, nullptr, Cp, DIMN, HD);
}

extern "C" void kernel_launch(void* const* d_in, const int* in_sizes, int n_in,
                              void* d_out, int out_size, void* d_ws, size_t ws_size,
                              hipStream_t stream) {
    const float* x    = (const float*)d_in[0];
    const float* fcos = (const float*)d_in[1];
    const float* fsin = (const float*)d_in[2];
    const float* wq   = (const float*)d_in[3];
    const float* bq   = (const float*)d_in[4];
    const float* wk   = (const float*)d_in[5];
    const float* bk   = (const float*)d_in[6];
    const float* wv   = (const float*)d_in[7];
    const float* bv   = (const float*)d_in[8];
    const float* wo   = (const float*)d_in[9];
    const float* bo   = (const float*)d_in[10];
    float* out = (float*)d_out;

    char* ws = (char*)d_ws;
    size_t off = 0;
    auto alloc = [&](size_t bytes) { char* p = ws + off; off += (bytes + 255) & ~(size_t)255; return p; };

    unsigned short* Xb   = (unsigned short*)alloc((size_t)ROWS * DIMN * 2);
    unsigned short* Wcat = (unsigned short*)alloc((size_t)NQKV * DIMN * 2);
    unsigned short* Wo2  = (unsigned short*)alloc((size_t)DIMN * DIMN * 2);
    unsigned short* QKV  = (unsigned short*)alloc((size_t)ROWS * NQKV * 2);
    float*          part = (float*)alloc((size_t)32 * 8 * HD * HD * 4);
    unsigned short* M2t  = (unsigned short*)alloc((size_t)32 * HD * HD * 2);
    unsigned short* W2   = (unsigned short*)alloc((size_t)BSZ * DIMN * DIMN * 2);

    // all converts in one launch
    cvt_all<<<24576, 256, 0, stream>>>(x, wq, wk, wv, wo, Xb, Wcat, Wo2);

    // QK projection + bias + RoPE  (M=4096, N=4096, K=2048): 256 blocks = 1 exact round
    gemm256d<0><<<256, 512, 0, stream>>>(
        Xb, DIMN, Wcat, DIMN, bq, bk, fcos, fsin, QKV, NQKV, DIMN);

    // V projection + bias  (M=4096, N=2048, K=2048): 256 blocks, BM256xBN128 (A/B test)
    gemm_v<<<256, 512, 0, stream>>>(
        Xb, DIMN, Wcat + (size_t)4096 * DIMN, DIMN, bv, QKV + 4096, NQKV, DIMN);

    // reassociated attention (no softmax): M2t = (K^T V)^T/sqrt(d) per (b,h)
    ktv_kernel<<<dim3(8, 32), 256, 0, stream>>>(QKV, part);
    ktv_reduce<<<(32 * 16384) / 256, 256, 0, stream>>>(part, M2t);

    // fold attention + output projection: W2_b = concat_h(Wo_h @ M2_{b,h})
    w2_gemm<<<dim3(16, 32), 256, 0, stream>>>(Wo2, M2t, W2);

    // out = Q @ W2_b^T + bo  (M=4096, N=2048 per batch, K=2048): 128 blocks (proven)
    gemm256d<2><<<128, 512, 0, stream>>>(
        QKV, NQKV, W2, DIMN, bo, nullptr, nullptr, nullptr, out, DIMN, DIMN);
}

// Round 18
// 187.986 us; speedup vs baseline: 1.3951x; 1.0656x over previous
//
#include <hip/hip_runtime.h>
#include <hip/hip_bf16.h>

#define DIMN 2048
#define NQKV 6144
#define NH 16
#define HD 128
#define BSZ 2
#define SEQ 2048
#define ROWS (BSZ*SEQ)   // 4096

typedef short short8 __attribute__((ext_vector_type(8)));
typedef float f32x4 __attribute__((ext_vector_type(4)));

__device__ __forceinline__ unsigned short f2bf(float f) {
    __hip_bfloat16 h = __float2bfloat16(f);
    unsigned short u; __builtin_memcpy(&u, &h, 2); return u;
}

__device__ __forceinline__ void gld_lds16(const void* g, void* l) {
    __builtin_amdgcn_global_load_lds(
        (const __attribute__((address_space(1))) void*)g,
        (__attribute__((address_space(3))) void*)l, 16, 0, 0);
}

// ---------------- fused f32 -> bf16 converts ----------------
__global__ void cvt_all(const float* __restrict__ x, const float* __restrict__ wq,
                        const float* __restrict__ wk, const float* __restrict__ wv,
                        const float* __restrict__ wo,
                        unsigned short* __restrict__ Xb, unsigned short* __restrict__ Wcat,
                        unsigned short* __restrict__ Wo2) {
    int bid = blockIdx.x;
    const float* in; unsigned short* out; int base;
    if      (bid <  8192) { in = x;  out = Xb;             base = bid; }
    else if (bid < 12288) { in = wq; out = Wcat;           base = bid - 8192; }
    else if (bid < 16384) { in = wk; out = Wcat + 4194304; base = bid - 12288; }
    else if (bid < 20480) { in = wv; out = Wcat + 8388608; base = bid - 16384; }
    else                  { in = wo; out = Wo2;            base = bid - 20480; }
    int i = (base * 256 + threadIdx.x) * 4;
    float4 v = *(const float4*)(in + i);
    ushort4 o; o.x = f2bf(v.x); o.y = f2bf(v.y); o.z = f2bf(v.z); o.w = f2bf(v.w);
    *(ushort4*)(out + i) = o;
}

// ========== QK: 256x256 de-convoyed GEMM (proven, 72.5us @ 941 TF) ==========
__global__ __launch_bounds__(512, 2) void gemm_qk(
    const unsigned short* __restrict__ A, int lda,
    const unsigned short* __restrict__ B, int ldb,
    const float* __restrict__ b0, const float* __restrict__ b1,
    const float* __restrict__ fcos, const float* __restrict__ fsin,
    unsigned short* __restrict__ C, int ldc, int K)
{
    __shared__ __align__(16) unsigned short As[32768];  // 64 KB: [2buf][2half][128][64]
    __shared__ __align__(16) unsigned short Bs[32768];  // 64 KB

    const int t  = threadIdx.x;
    const int l  = t & 63;
    const int w  = t >> 6;
    const int wr = w >> 2;
    const int wc = w & 3;
    const int fr = l & 15, fq = l >> 4;

    const int xcd = blockIdx.x & 7;
    const int j   = blockIdx.x >> 3;
    const int mt  = (xcd & 1) * 8 + (j >> 2);
    const int nt  = (xcd >> 1) * 4 + (j & 3);
    const int m0 = mt * 256;
    const int n0 = nt * 256;

    const int srow = t >> 3;
    const int scol = ((t & 7) ^ (srow & 7)) * 8;
    const unsigned short* aS = A + (size_t)(m0 + srow) * lda + scol;
    const unsigned short* bS = B + (size_t)(n0 + srow) * ldb + scol;

#define STG_A(KT, H) do { \
    const unsigned short* s_ = aS + (size_t)(H) * 128 * lda + (size_t)(KT) * 64; \
    gld_lds16(s_,                    &As[(((KT) & 1) << 14) + ((H) << 13) + t * 8]); \
    gld_lds16(s_ + (size_t)64 * lda, &As[(((KT) & 1) << 14) + ((H) << 13) + 4096 + t * 8]); \
  } while (0)
#define STG_B(KT, H) do { \
    const unsigned short* s_ = bS + (size_t)(H) * 128 * ldb + (size_t)(KT) * 64; \
    gld_lds16(s_,                    &Bs[(((KT) & 1) << 14) + ((H) << 13) + t * 8]); \
    gld_lds16(s_ + (size_t)64 * ldb, &Bs[(((KT) & 1) << 14) + ((H) << 13) + 4096 + t * 8]); \
  } while (0)

    const int cK0 = (fq ^ (fr & 7)) * 8;
    const int cK1 = ((4 + fq) ^ (fr & 7)) * 8;
    const int aB0 = wr * 8192 + fr * 64;
    const int bB0 = wc * 4096 + fr * 64;

    const unsigned aA0 = (unsigned)(size_t)&As[aB0 + cK0];
    const unsigned aA1 = (unsigned)(size_t)&As[aB0 + cK1];
    const unsigned bA0 = (unsigned)(size_t)&Bs[bB0 + cK0];
    const unsigned bA1 = (unsigned)(size_t)&Bs[bB0 + cK1];

    short8 aF[4][2], bF0[2][2], bF1[2][2];
    f32x4  acc[8][4] = {};

#define DSR(dst, areg, OFF) \
    asm volatile("ds_read_b128 %0, %1 offset:%2" : "=v"(dst) : "v"(areg), "n"(OFF))

#define RD_A(DDB, QM) do { \
    DSR(aF[0][0], aA0, (DDB) + (QM) * 8192 + 0);    DSR(aF[0][1], aA1, (DDB) + (QM) * 8192 + 0); \
    DSR(aF[1][0], aA0, (DDB) + (QM) * 8192 + 2048); DSR(aF[1][1], aA1, (DDB) + (QM) * 8192 + 2048); \
    DSR(aF[2][0], aA0, (DDB) + (QM) * 8192 + 4096); DSR(aF[2][1], aA1, (DDB) + (QM) * 8192 + 4096); \
    DSR(aF[3][0], aA0, (DDB) + (QM) * 8192 + 6144); DSR(aF[3][1], aA1, (DDB) + (QM) * 8192 + 6144); \
  } while (0)
#define RD_B(DDB, QN, BF) do { \
    DSR(BF[0][0], bA0, (DDB) + (QN) * 4096 + 0);    DSR(BF[0][1], bA1, (DDB) + (QN) * 4096 + 0); \
    DSR(BF[1][0], bA0, (DDB) + (QN) * 4096 + 2048); DSR(BF[1][1], bA1, (DDB) + (QN) * 4096 + 2048); \
  } while (0)

#define BAR() asm volatile("s_barrier" ::: "memory")

#define MM(QM, QN, BF) do { \
    _Pragma("unroll") for (int m2 = 0; m2 < 4; ++m2) \
      _Pragma("unroll") for (int n2 = 0; n2 < 2; ++n2) { \
        acc[(QM)*4+m2][(QN)*2+n2] = __builtin_amdgcn_mfma_f32_16x16x32_bf16( \
            aF[m2][0], BF[n2][0], acc[(QM)*4+m2][(QN)*2+n2], 0, 0, 0); \
        acc[(QM)*4+m2][(QN)*2+n2] = __builtin_amdgcn_mfma_f32_16x16x32_bf16( \
            aF[m2][1], BF[n2][1], acc[(QM)*4+m2][(QN)*2+n2], 0, 0, 0); } \
  } while (0)

#define TILE(KT, DDB) do { \
    if ((KT) + 1 < ktT) { \
        STG_A((KT) + 1, 0); STG_A((KT) + 1, 1); \
        STG_B((KT) + 1, 0); STG_B((KT) + 1, 1); \
    } \
    RD_A(DDB, 0); RD_B(DDB, 0, bF0); RD_B(DDB, 1, bF1); \
    asm volatile("s_waitcnt lgkmcnt(4)"); \
    __builtin_amdgcn_sched_barrier(0); \
    __builtin_amdgcn_s_setprio(1); \
    MM(0, 0, bF0); \
    asm volatile("s_waitcnt lgkmcnt(0)"); \
    __builtin_amdgcn_sched_barrier(0); \
    MM(0, 1, bF1); \
    __builtin_amdgcn_s_setprio(0); \
    RD_A(DDB, 1); \
    asm volatile("s_waitcnt lgkmcnt(0)"); \
    __builtin_amdgcn_sched_barrier(0); \
    __builtin_amdgcn_s_setprio(1); \
    MM(1, 0, bF0); MM(1, 1, bF1); \
    __builtin_amdgcn_s_setprio(0); \
    asm volatile("s_waitcnt vmcnt(0)"); \
    __builtin_amdgcn_sched_barrier(0); \
    BAR(); \
  } while (0)

    const int ktT = K >> 6;   // 32

    STG_A(0, 0); STG_A(0, 1);
    STG_B(0, 0); STG_B(0, 1);
    asm volatile("s_waitcnt vmcnt(0)");
    __builtin_amdgcn_sched_barrier(0);
    BAR();

    for (int kt = 0; kt < ktT; kt += 2) {
        TILE(kt, 0);
        TILE(kt + 1, 32768);
    }

#undef TILE
#undef MM
#undef BAR
#undef RD_A
#undef RD_B
#undef DSR
#undef STG_A
#undef STG_B

    // ---- epilogue: bias + RoPE, bf16 store
    #pragma unroll
    for (int mi = 0; mi < 8; ++mi) {
        #pragma unroll
        for (int ni = 0; ni < 4; ++ni) {
            #pragma unroll
            for (int j2 = 0; j2 < 4; ++j2) {
                const int r  = m0 + wr * 128 + mi * 16 + fq * 4 + j2;
                const int cg = n0 + wc * 64 + ni * 16 + fr;
                float v = acc[mi][ni][j2];
                v += (cg < 2048) ? b0[cg] : b1[cg - 2048];
                const int s = r & (SEQ - 1);
                const int i = (cg >> 1) & 63;
                const float cs = fcos[s * 64 + i];
                const float sn = fsin[s * 64 + i];
                const float p  = __shfl_xor(v, 1);
                v = (fr & 1) ? (p * sn + v * cs) : (v * cs - p * sn);
                C[(size_t)r * ldc + cg] = f2bf(v);
            }
        }
    }
}

// ========== BM=256 x BN=128, 256-block de-convoyed engine (r17 winner, ~34us) ==========
// EPI 0: V   (bf16 out + bias)
// EPI 1: out (f32 out + bias, B=W2 selected per batch on m0)
template<int EPI>
__global__ __launch_bounds__(512, 2) void gemm_n128(
    const unsigned short* __restrict__ A, int lda,
    const unsigned short* __restrict__ B, int ldb,
    const float* __restrict__ bias,
    void* __restrict__ C, int ldc, int K)
{
    __shared__ __align__(16) unsigned short As[32768];  // 64 KB: [2buf][2half][128][64]
    __shared__ __align__(16) unsigned short Bs[16384];  // 32 KB: [2buf][128][64]

    const int t  = threadIdx.x;
    const int l  = t & 63;
    const int w  = t >> 6;
    const int wr = w >> 2;          // 0..1 (128-row half)
    const int wc = w & 3;           // 0..3 (32-col quarter)
    const int fr = l & 15, fq = l >> 4;

    const int xcd = blockIdx.x & 7;
    const int j   = blockIdx.x >> 3;          // 0..31
    const int mt  = (xcd & 3) * 4 + (j >> 3); // 0..15
    const int nt  = (xcd >> 2) * 8 + (j & 7); // 0..15
    const int m0 = mt * 256;
    const int n0 = nt * 128;

    const unsigned short* Bsel = B;
    if (EPI == 1 && m0 >= 2048) Bsel += (size_t)2048 * 2048;  // per-batch W2

    const int srow = t >> 3;
    const int scol = ((t & 7) ^ (srow & 7)) * 8;
    const unsigned short* aS = A    + (size_t)(m0 + srow) * lda + scol;
    const unsigned short* bS = Bsel + (size_t)(n0 + srow) * ldb + scol;

#define VSTG_A(KT, H) do { \
    const unsigned short* s_ = aS + (size_t)(H) * 128 * lda + (size_t)(KT) * 64; \
    gld_lds16(s_,                    &As[(((KT) & 1) << 14) + ((H) << 13) + t * 8]); \
    gld_lds16(s_ + (size_t)64 * lda, &As[(((KT) & 1) << 14) + ((H) << 13) + 4096 + t * 8]); \
  } while (0)
#define VSTG_B(KT) do { \
    const unsigned short* s_ = bS + (size_t)(KT) * 64; \
    gld_lds16(s_,                    &Bs[(((KT) & 1) << 13) + t * 8]); \
    gld_lds16(s_ + (size_t)64 * ldb, &Bs[(((KT) & 1) << 13) + 4096 + t * 8]); \
  } while (0)

    const int cK0 = (fq ^ (fr & 7)) * 8;
    const int cK1 = ((4 + fq) ^ (fr & 7)) * 8;
    const int aB0 = wr * 8192 + fr * 64;
    const int bB0 = wc * 2048 + fr * 64;

    const unsigned aA0 = (unsigned)(size_t)&As[aB0 + cK0];
    const unsigned aA1 = (unsigned)(size_t)&As[aB0 + cK1];
    const unsigned bA0 = (unsigned)(size_t)&Bs[bB0 + cK0];
    const unsigned bA1 = (unsigned)(size_t)&Bs[bB0 + cK1];

    short8 aF[4][2], bF0[2], bF1[2];
    f32x4  acc[8][2] = {};

#define VDSR(dst, areg, OFF) \
    asm volatile("ds_read_b128 %0, %1 offset:%2" : "=v"(dst) : "v"(areg), "n"(OFF))

#define VRD_A(DA, QM) do { \
    VDSR(aF[0][0], aA0, (DA) + (QM) * 8192 + 0);    VDSR(aF[0][1], aA1, (DA) + (QM) * 8192 + 0); \
    VDSR(aF[1][0], aA0, (DA) + (QM) * 8192 + 2048); VDSR(aF[1][1], aA1, (DA) + (QM) * 8192 + 2048); \
    VDSR(aF[2][0], aA0, (DA) + (QM) * 8192 + 4096); VDSR(aF[2][1], aA1, (DA) + (QM) * 8192 + 4096); \
    VDSR(aF[3][0], aA0, (DA) + (QM) * 8192 + 6144); VDSR(aF[3][1], aA1, (DA) + (QM) * 8192 + 6144); \
  } while (0)
#define VRD_B(DB, NI, BF) do { \
    VDSR(BF[0], bA0, (DB) + (NI) * 2048); VDSR(BF[1], bA1, (DB) + (NI) * 2048); \
  } while (0)

#define VBAR() asm volatile("s_barrier" ::: "memory")

#define VMM(QM, NI, BF) do { \
    _Pragma("unroll") for (int m2 = 0; m2 < 4; ++m2) { \
        acc[(QM)*4+m2][NI] = __builtin_amdgcn_mfma_f32_16x16x32_bf16( \
            aF[m2][0], BF[0], acc[(QM)*4+m2][NI], 0, 0, 0); \
        acc[(QM)*4+m2][NI] = __builtin_amdgcn_mfma_f32_16x16x32_bf16( \
            aF[m2][1], BF[1], acc[(QM)*4+m2][NI], 0, 0, 0); } \
  } while (0)

#define VTILE(KT, DA, DB) do { \
    if ((KT) + 1 < ktT) { \
        VSTG_A((KT) + 1, 0); VSTG_A((KT) + 1, 1); VSTG_B((KT) + 1); \
    } \
    VRD_A(DA, 0); VRD_B(DB, 0, bF0); VRD_B(DB, 1, bF1); \
    asm volatile("s_waitcnt lgkmcnt(2)"); \
    __builtin_amdgcn_sched_barrier(0); \
    __builtin_amdgcn_s_setprio(1); \
    VMM(0, 0, bF0); \
    asm volatile("s_waitcnt lgkmcnt(0)"); \
    __builtin_amdgcn_sched_barrier(0); \
    VMM(0, 1, bF1); \
    __builtin_amdgcn_s_setprio(0); \
    VRD_A(DA, 1); \
    asm volatile("s_waitcnt lgkmcnt(0)"); \
    __builtin_amdgcn_sched_barrier(0); \
    __builtin_amdgcn_s_setprio(1); \
    VMM(1, 0, bF0); VMM(1, 1, bF1); \
    __builtin_amdgcn_s_setprio(0); \
    asm volatile("s_waitcnt vmcnt(0)"); \
    __builtin_amdgcn_sched_barrier(0); \
    VBAR(); \
  } while (0)

    const int ktT = K >> 6;   // 32

    VSTG_A(0, 0); VSTG_A(0, 1); VSTG_B(0);
    asm volatile("s_waitcnt vmcnt(0)");
    __builtin_amdgcn_sched_barrier(0);
    VBAR();

    for (int kt = 0; kt < ktT; kt += 2) {
        VTILE(kt, 0, 0);
        VTILE(kt + 1, 32768, 16384);
    }

#undef VTILE
#undef VMM
#undef VBAR
#undef VRD_A
#undef VRD_B
#undef VDSR
#undef VSTG_A
#undef VSTG_B

    // ---- epilogue
    #pragma unroll
    for (int mi = 0; mi < 8; ++mi) {
        #pragma unroll
        for (int ni = 0; ni < 2; ++ni) {
            #pragma unroll
            for (int j2 = 0; j2 < 4; ++j2) {
                const int r  = m0 + wr * 128 + mi * 16 + fq * 4 + j2;
                const int cg = n0 + wc * 32 + ni * 16 + fr;
                float v = acc[mi][ni][j2] + bias[cg];
                if (EPI == 0) ((unsigned short*)C)[(size_t)r * ldc + cg] = f2bf(v);
                else          ((float*)C)[(size_t)r * ldc + cg] = v;
            }
        }
    }
}

// ---------------- 128x128 GEMM core (small GEMMs) ----------------
template<int OUT_BF16, int HAS_BIAS>
__device__ __forceinline__ void gemm_tile_core(
    const unsigned short* __restrict__ A, int lda,
    const unsigned short* __restrict__ B, int ldb,
    const float* __restrict__ bias,
    void* __restrict__ Cptr, int ldc, int K)
{
    __shared__ __align__(16) unsigned short As[128 * 64];
    __shared__ __align__(16) unsigned short Bs[128 * 64];

    const int t  = threadIdx.x;
    const int l  = t & 63;
    const int w  = t >> 6;
    const int wr = w >> 1, wc = w & 1;
    const int fr = l & 15, fq = l >> 4;

    f32x4 acc[4][4] = {};

    const int srow = t >> 3;
    const int scol = (t & 7) * 8;

    for (int k0 = 0; k0 < K; k0 += 64) {
        __syncthreads();
        #pragma unroll
        for (int r = 0; r < 4; ++r) {
            gld_lds16(A + (size_t)(r * 32 + srow) * lda + k0 + scol, &As[(r * 32 + srow) * 64 + scol]);
            gld_lds16(B + (size_t)(r * 32 + srow) * ldb + k0 + scol, &Bs[(r * 32 + srow) * 64 + scol]);
        }
        __syncthreads();
        #pragma unroll
        for (int kk = 0; kk < 2; ++kk) {
            short8 a[4], b[4];
            #pragma unroll
            for (int mi = 0; mi < 4; ++mi)
                a[mi] = *(const short8*)&As[(wr * 64 + mi * 16 + fr) * 64 + kk * 32 + fq * 8];
            #pragma unroll
            for (int ni = 0; ni < 4; ++ni)
                b[ni] = *(const short8*)&Bs[(wc * 64 + ni * 16 + fr) * 64 + kk * 32 + fq * 8];
            #pragma unroll
            for (int mi = 0; mi < 4; ++mi)
                #pragma unroll
                for (int ni = 0; ni < 4; ++ni)
                    acc[mi][ni] = __builtin_amdgcn_mfma_f32_16x16x32_bf16(a[mi], b[ni], acc[mi][ni], 0, 0, 0);
        }
    }

    #pragma unroll
    for (int mi = 0; mi < 4; ++mi) {
        #pragma unroll
        for (int ni = 0; ni < 4; ++ni) {
            #pragma unroll
            for (int j = 0; j < 4; ++j) {
                int rr = wr * 64 + mi * 16 + fq * 4 + j;
                int cc = wc * 64 + ni * 16 + fr;
                float v = acc[mi][ni][j];
                if (HAS_BIAS) v += bias[cc];
                if (OUT_BF16) ((unsigned short*)Cptr)[(size_t)rr * ldc + cc] = f2bf(v);
                else          ((float*)Cptr)[(size_t)rr * ldc + cc] = v;
            }
        }
    }
}

// ---------------- K^T/V partials ----------------
__global__ __launch_bounds__(256) void ktv_kernel(
    const unsigned short* __restrict__ QKV, float* __restrict__ part)
{
    const int ks = blockIdx.x;
    const int bh = blockIdx.y;
    const int b = bh >> 4, h = bh & 15;
    const unsigned short* Kbase = QKV + (size_t)(b * SEQ + ks * 256) * NQKV + 2048 + h * HD;
    const unsigned short* Vbase = QKV + (size_t)(b * SEQ + ks * 256) * NQKV + 4096 + h * HD;

    __shared__ __align__(16) unsigned short Ks_[64 * 128];
    __shared__ __align__(16) unsigned short Vs_[64 * 128];

    const int t  = threadIdx.x;
    const int l  = t & 63;
    const int w  = t >> 6;
    const int wr = w >> 1, wc = w & 1;
    const int fr = l & 15, fq = l >> 4;

    f32x4 acc[4][4] = {};

    const int srow = t >> 4;
    const int scol = (t & 15) * 8;

    for (int sc = 0; sc < 4; ++sc) {
        __syncthreads();
        #pragma unroll
        for (int r = 0; r < 4; ++r) {
            gld_lds16(Kbase + (size_t)(sc * 64 + r * 16 + srow) * NQKV + scol, &Ks_[(r * 16 + srow) * 128 + scol]);
            gld_lds16(Vbase + (size_t)(sc * 64 + r * 16 + srow) * NQKV + scol, &Vs_[(r * 16 + srow) * 128 + scol]);
        }
        __syncthreads();
        #pragma unroll
        for (int kk = 0; kk < 2; ++kk) {
            short8 a[4], bb[4];
            #pragma unroll
            for (int mi = 0; mi < 4; ++mi)
                #pragma unroll
                for (int i = 0; i < 8; ++i)
                    a[mi][i] = (short)Ks_[(kk * 32 + fq * 8 + i) * 128 + wr * 64 + mi * 16 + fr];
            #pragma unroll
            for (int ni = 0; ni < 4; ++ni)
                #pragma unroll
                for (int i = 0; i < 8; ++i)
                    bb[ni][i] = (short)Vs_[(kk * 32 + fq * 8 + i) * 128 + wc * 64 + ni * 16 + fr];
            #pragma unroll
            for (int mi = 0; mi < 4; ++mi)
                #pragma unroll
                for (int ni = 0; ni < 4; ++ni)
                    acc[mi][ni] = __builtin_amdgcn_mfma_f32_16x16x32_bf16(a[mi], bb[ni], acc[mi][ni], 0, 0, 0);
        }
    }

    float* base = part + ((size_t)bh * 8 + ks) * 16384;
    #pragma unroll
    for (int mi = 0; mi < 4; ++mi)
        #pragma unroll
        for (int ni = 0; ni < 4; ++ni)
            #pragma unroll
            for (int j = 0; j < 4; ++j)
                base[(wr * 64 + mi * 16 + fq * 4 + j) * 128 + wc * 64 + ni * 16 + fr] = acc[mi][ni][j];
}

// ---------------- reduce partials ----------------
__global__ void ktv_reduce(const float* __restrict__ part, unsigned short* __restrict__ M2t) {
    int idx = blockIdx.x * 256 + threadIdx.x;
    int bh = idx >> 14, rem = idx & 16383;
    const float* p = part + ((size_t)bh * 8) * 16384 + rem;
    float s = 0.f;
    #pragma unroll
    for (int k = 0; k < 8; ++k) s += p[(size_t)k * 16384];
    M2t[idx] = f2bf(s * 0.08838834764831845f);
}

// ---------------- W2 fold ----------------
__global__ __launch_bounds__(256) void w2_gemm(
    const unsigned short* __restrict__ Wo2, const unsigned short* __restrict__ M2t,
    unsigned short* __restrict__ W2)
{
    const int mt = blockIdx.x;
    const int bh = blockIdx.y;
    const int b = bh >> 4, h = bh & 15;
    const unsigned short* A = Wo2 + (size_t)(mt * 128) * DIMN + h * HD;
    const unsigned short* B = M2t + (size_t)bh * HD * HD;
    unsigned short* Cp = W2 + (size_t)b * DIMN * DIMN + (size_t)(mt * 128) * DIMN + h * HD;
    gemm_tile_core<1, 0>(A, DIMN, B, HD, nullptr, Cp, DIMN, HD);
}

extern "C" void kernel_launch(void* const* d_in, const int* in_sizes, int n_in,
                              void* d_out, int out_size, void* d_ws, size_t ws_size,
                              hipStream_t stream) {
    const float* x    = (const float*)d_in[0];
    const float* fcos = (const float*)d_in[1];
    const float* fsin = (const float*)d_in[2];
    const float* wq   = (const float*)d_in[3];
    const float* bq   = (const float*)d_in[4];
    const float* wk   = (const float*)d_in[5];
    const float* bk   = (const float*)d_in[6];
    const float* wv   = (const float*)d_in[7];
    const float* bv   = (const float*)d_in[8];
    const float* wo   = (const float*)d_in[9];
    const float* bo   = (const float*)d_in[10];
    float* out = (float*)d_out;

    char* ws = (char*)d_ws;
    size_t off = 0;
    auto alloc = [&](size_t bytes) { char* p = ws + off; off += (bytes + 255) & ~(size_t)255; return p; };

    unsigned short* Xb   = (unsigned short*)alloc((size_t)ROWS * DIMN * 2);
    unsigned short* Wcat = (unsigned short*)alloc((size_t)NQKV * DIMN * 2);
    unsigned short* Wo2  = (unsigned short*)alloc((size_t)DIMN * DIMN * 2);
    unsigned short* QKV  = (unsigned short*)alloc((size_t)ROWS * NQKV * 2);
    float*          part = (float*)alloc((size_t)32 * 8 * HD * HD * 4);
    unsigned short* M2t  = (unsigned short*)alloc((size_t)32 * HD * HD * 2);
    unsigned short* W2   = (unsigned short*)alloc((size_t)BSZ * DIMN * DIMN * 2);

    // all converts in one launch
    cvt_all<<<24576, 256, 0, stream>>>(x, wq, wk, wv, wo, Xb, Wcat, Wo2);

    // QK projection + bias + RoPE  (M=4096, N=4096, K=2048): 256 blocks
    gemm_qk<<<256, 512, 0, stream>>>(
        Xb, DIMN, Wcat, DIMN, bq, bk, fcos, fsin, QKV, NQKV, DIMN);

    // V projection + bias  (M=4096, N=2048, K=2048): 256 blocks BM256xBN128 (proven ~34us)
    gemm_n128<0><<<256, 512, 0, stream>>>(
        Xb, DIMN, Wcat + (size_t)4096 * DIMN, DIMN, bv, QKV + 4096, NQKV, DIMN);

    // reassociated attention (no softmax): M2t = (K^T V)^T/sqrt(d) per (b,h)
    ktv_kernel<<<dim3(8, 32), 256, 0, stream>>>(QKV, part);
    ktv_reduce<<<(32 * 16384) / 256, 256, 0, stream>>>(part, M2t);

    // fold attention + output projection: W2_b = concat_h(Wo_h @ M2_{b,h})
    w2_gemm<<<dim3(16, 32), 256, 0, stream>>>(Wo2, M2t, W2);

    // out = Q @ W2_b^T + bo  (M=4096, N=2048, K=2048): 256 blocks BM256xBN128 (ported)
    gemm_n128<1><<<256, 512, 0, stream>>>(
        QKV, NQKV, W2, DIMN, bo, out, DIMN, DIMN);
}

// Round 19
// 186.318 us; speedup vs baseline: 1.4076x; 1.0090x over previous
//
#include <hip/hip_runtime.h>
#include <hip/hip_bf16.h>

#define DIMN 2048
#define NQKV 6144
#define NH 16
#define HD 128
#define BSZ 2
#define SEQ 2048
#define ROWS (BSZ*SEQ)   // 4096

typedef short short8 __attribute__((ext_vector_type(8)));
typedef float f32x4 __attribute__((ext_vector_type(4)));

__device__ __forceinline__ unsigned short f2bf(float f) {
    __hip_bfloat16 h = __float2bfloat16(f);
    unsigned short u; __builtin_memcpy(&u, &h, 2); return u;
}

__device__ __forceinline__ void gld_lds16(const void* g, void* l) {
    __builtin_amdgcn_global_load_lds(
        (const __attribute__((address_space(1))) void*)g,
        (__attribute__((address_space(3))) void*)l, 16, 0, 0);
}

// ---------------- fused f32 -> bf16 converts ----------------
__global__ void cvt_all(const float* __restrict__ x, const float* __restrict__ wq,
                        const float* __restrict__ wk, const float* __restrict__ wv,
                        const float* __restrict__ wo,
                        unsigned short* __restrict__ Xb, unsigned short* __restrict__ Wcat,
                        unsigned short* __restrict__ Wo2) {
    int bid = blockIdx.x;
    const float* in; unsigned short* out; int base;
    if      (bid <  8192) { in = x;  out = Xb;             base = bid; }
    else if (bid < 12288) { in = wq; out = Wcat;           base = bid - 8192; }
    else if (bid < 16384) { in = wk; out = Wcat + 4194304; base = bid - 12288; }
    else if (bid < 20480) { in = wv; out = Wcat + 8388608; base = bid - 16384; }
    else                  { in = wo; out = Wo2;            base = bid - 20480; }
    int i = (base * 256 + threadIdx.x) * 4;
    float4 v = *(const float4*)(in + i);
    ushort4 o; o.x = f2bf(v.x); o.y = f2bf(v.y); o.z = f2bf(v.z); o.w = f2bf(v.w);
    *(ushort4*)(out + i) = o;
}

// ========== QK: 256x256 de-convoyed GEMM (proven, 72.5us @ 941 TF) ==========
__global__ __launch_bounds__(512, 2) void gemm_qk(
    const unsigned short* __restrict__ A, int lda,
    const unsigned short* __restrict__ B, int ldb,
    const float* __restrict__ b0, const float* __restrict__ b1,
    const float* __restrict__ fcos, const float* __restrict__ fsin,
    unsigned short* __restrict__ C, int ldc, int K)
{
    __shared__ __align__(16) unsigned short As[32768];  // 64 KB: [2buf][2half][128][64]
    __shared__ __align__(16) unsigned short Bs[32768];  // 64 KB

    const int t  = threadIdx.x;
    const int l  = t & 63;
    const int w  = t >> 6;
    const int wr = w >> 2;
    const int wc = w & 3;
    const int fr = l & 15, fq = l >> 4;

    const int xcd = blockIdx.x & 7;
    const int j   = blockIdx.x >> 3;
    const int mt  = (xcd & 1) * 8 + (j >> 2);
    const int nt  = (xcd >> 1) * 4 + (j & 3);
    const int m0 = mt * 256;
    const int n0 = nt * 256;

    const int srow = t >> 3;
    const int scol = ((t & 7) ^ (srow & 7)) * 8;
    const unsigned short* aS = A + (size_t)(m0 + srow) * lda + scol;
    const unsigned short* bS = B + (size_t)(n0 + srow) * ldb + scol;

#define STG_A(KT, H) do { \
    const unsigned short* s_ = aS + (size_t)(H) * 128 * lda + (size_t)(KT) * 64; \
    gld_lds16(s_,                    &As[(((KT) & 1) << 14) + ((H) << 13) + t * 8]); \
    gld_lds16(s_ + (size_t)64 * lda, &As[(((KT) & 1) << 14) + ((H) << 13) + 4096 + t * 8]); \
  } while (0)
#define STG_B(KT, H) do { \
    const unsigned short* s_ = bS + (size_t)(H) * 128 * ldb + (size_t)(KT) * 64; \
    gld_lds16(s_,                    &Bs[(((KT) & 1) << 14) + ((H) << 13) + t * 8]); \
    gld_lds16(s_ + (size_t)64 * ldb, &Bs[(((KT) & 1) << 14) + ((H) << 13) + 4096 + t * 8]); \
  } while (0)

    const int cK0 = (fq ^ (fr & 7)) * 8;
    const int cK1 = ((4 + fq) ^ (fr & 7)) * 8;
    const int aB0 = wr * 8192 + fr * 64;
    const int bB0 = wc * 4096 + fr * 64;

    const unsigned aA0 = (unsigned)(size_t)&As[aB0 + cK0];
    const unsigned aA1 = (unsigned)(size_t)&As[aB0 + cK1];
    const unsigned bA0 = (unsigned)(size_t)&Bs[bB0 + cK0];
    const unsigned bA1 = (unsigned)(size_t)&Bs[bB0 + cK1];

    short8 aF[4][2], bF0[2][2], bF1[2][2];
    f32x4  acc[8][4] = {};

#define DSR(dst, areg, OFF) \
    asm volatile("ds_read_b128 %0, %1 offset:%2" : "=v"(dst) : "v"(areg), "n"(OFF))

#define RD_A(DDB, QM) do { \
    DSR(aF[0][0], aA0, (DDB) + (QM) * 8192 + 0);    DSR(aF[0][1], aA1, (DDB) + (QM) * 8192 + 0); \
    DSR(aF[1][0], aA0, (DDB) + (QM) * 8192 + 2048); DSR(aF[1][1], aA1, (DDB) + (QM) * 8192 + 2048); \
    DSR(aF[2][0], aA0, (DDB) + (QM) * 8192 + 4096); DSR(aF[2][1], aA1, (DDB) + (QM) * 8192 + 4096); \
    DSR(aF[3][0], aA0, (DDB) + (QM) * 8192 + 6144); DSR(aF[3][1], aA1, (DDB) + (QM) * 8192 + 6144); \
  } while (0)
#define RD_B(DDB, QN, BF) do { \
    DSR(BF[0][0], bA0, (DDB) + (QN) * 4096 + 0);    DSR(BF[0][1], bA1, (DDB) + (QN) * 4096 + 0); \
    DSR(BF[1][0], bA0, (DDB) + (QN) * 4096 + 2048); DSR(BF[1][1], bA1, (DDB) + (QN) * 4096 + 2048); \
  } while (0)

#define BAR() asm volatile("s_barrier" ::: "memory")

#define MM(QM, QN, BF) do { \
    _Pragma("unroll") for (int m2 = 0; m2 < 4; ++m2) \
      _Pragma("unroll") for (int n2 = 0; n2 < 2; ++n2) { \
        acc[(QM)*4+m2][(QN)*2+n2] = __builtin_amdgcn_mfma_f32_16x16x32_bf16( \
            aF[m2][0], BF[n2][0], acc[(QM)*4+m2][(QN)*2+n2], 0, 0, 0); \
        acc[(QM)*4+m2][(QN)*2+n2] = __builtin_amdgcn_mfma_f32_16x16x32_bf16( \
            aF[m2][1], BF[n2][1], acc[(QM)*4+m2][(QN)*2+n2], 0, 0, 0); } \
  } while (0)

#define TILE(KT, DDB) do { \
    if ((KT) + 1 < ktT) { \
        STG_A((KT) + 1, 0); STG_A((KT) + 1, 1); \
        STG_B((KT) + 1, 0); STG_B((KT) + 1, 1); \
    } \
    RD_A(DDB, 0); RD_B(DDB, 0, bF0); RD_B(DDB, 1, bF1); \
    asm volatile("s_waitcnt lgkmcnt(4)"); \
    __builtin_amdgcn_sched_barrier(0); \
    __builtin_amdgcn_s_setprio(1); \
    MM(0, 0, bF0); \
    asm volatile("s_waitcnt lgkmcnt(0)"); \
    __builtin_amdgcn_sched_barrier(0); \
    MM(0, 1, bF1); \
    __builtin_amdgcn_s_setprio(0); \
    RD_A(DDB, 1); \
    asm volatile("s_waitcnt lgkmcnt(0)"); \
    __builtin_amdgcn_sched_barrier(0); \
    __builtin_amdgcn_s_setprio(1); \
    MM(1, 0, bF0); MM(1, 1, bF1); \
    __builtin_amdgcn_s_setprio(0); \
    asm volatile("s_waitcnt vmcnt(0)"); \
    __builtin_amdgcn_sched_barrier(0); \
    BAR(); \
  } while (0)

    const int ktT = K >> 6;   // 32

    STG_A(0, 0); STG_A(0, 1);
    STG_B(0, 0); STG_B(0, 1);
    asm volatile("s_waitcnt vmcnt(0)");
    __builtin_amdgcn_sched_barrier(0);
    BAR();

    for (int kt = 0; kt < ktT; kt += 2) {
        TILE(kt, 0);
        TILE(kt + 1, 32768);
    }

#undef TILE
#undef MM
#undef BAR
#undef RD_A
#undef RD_B
#undef DSR
#undef STG_A
#undef STG_B

    // ---- epilogue: bias + RoPE, bf16 store
    #pragma unroll
    for (int mi = 0; mi < 8; ++mi) {
        #pragma unroll
        for (int ni = 0; ni < 4; ++ni) {
            #pragma unroll
            for (int j2 = 0; j2 < 4; ++j2) {
                const int r  = m0 + wr * 128 + mi * 16 + fq * 4 + j2;
                const int cg = n0 + wc * 64 + ni * 16 + fr;
                float v = acc[mi][ni][j2];
                v += (cg < 2048) ? b0[cg] : b1[cg - 2048];
                const int s = r & (SEQ - 1);
                const int i = (cg >> 1) & 63;
                const float cs = fcos[s * 64 + i];
                const float sn = fsin[s * 64 + i];
                const float p  = __shfl_xor(v, 1);
                v = (fr & 1) ? (p * sn + v * cs) : (v * cs - p * sn);
                C[(size_t)r * ldc + cg] = f2bf(v);
            }
        }
    }
}

// ========== BM=256 x BN=128, 256-block de-convoyed engine (r17 winner, ~34us) ==========
// EPI 0: V   (bf16 out + bias)
// EPI 1: out (f32 out + bias, B=W2 selected per batch on m0)
template<int EPI>
__global__ __launch_bounds__(512, 2) void gemm_n128(
    const unsigned short* __restrict__ A, int lda,
    const unsigned short* __restrict__ B, int ldb,
    const float* __restrict__ bias,
    void* __restrict__ C, int ldc, int K)
{
    __shared__ __align__(16) unsigned short As[32768];  // 64 KB: [2buf][2half][128][64]
    __shared__ __align__(16) unsigned short Bs[16384];  // 32 KB: [2buf][128][64]

    const int t  = threadIdx.x;
    const int l  = t & 63;
    const int w  = t >> 6;
    const int wr = w >> 2;          // 0..1 (128-row half)
    const int wc = w & 3;           // 0..3 (32-col quarter)
    const int fr = l & 15, fq = l >> 4;

    const int xcd = blockIdx.x & 7;
    const int j   = blockIdx.x >> 3;          // 0..31
    const int mt  = (xcd & 3) * 4 + (j >> 3); // 0..15
    const int nt  = (xcd >> 2) * 8 + (j & 7); // 0..15
    const int m0 = mt * 256;
    const int n0 = nt * 128;

    const unsigned short* Bsel = B;
    if (EPI == 1 && m0 >= 2048) Bsel += (size_t)2048 * 2048;  // per-batch W2

    const int srow = t >> 3;
    const int scol = ((t & 7) ^ (srow & 7)) * 8;
    const unsigned short* aS = A    + (size_t)(m0 + srow) * lda + scol;
    const unsigned short* bS = Bsel + (size_t)(n0 + srow) * ldb + scol;

#define VSTG_A(KT, H) do { \
    const unsigned short* s_ = aS + (size_t)(H) * 128 * lda + (size_t)(KT) * 64; \
    gld_lds16(s_,                    &As[(((KT) & 1) << 14) + ((H) << 13) + t * 8]); \
    gld_lds16(s_ + (size_t)64 * lda, &As[(((KT) & 1) << 14) + ((H) << 13) + 4096 + t * 8]); \
  } while (0)
#define VSTG_B(KT) do { \
    const unsigned short* s_ = bS + (size_t)(KT) * 64; \
    gld_lds16(s_,                    &Bs[(((KT) & 1) << 13) + t * 8]); \
    gld_lds16(s_ + (size_t)64 * ldb, &Bs[(((KT) & 1) << 13) + 4096 + t * 8]); \
  } while (0)

    const int cK0 = (fq ^ (fr & 7)) * 8;
    const int cK1 = ((4 + fq) ^ (fr & 7)) * 8;
    const int aB0 = wr * 8192 + fr * 64;
    const int bB0 = wc * 2048 + fr * 64;

    const unsigned aA0 = (unsigned)(size_t)&As[aB0 + cK0];
    const unsigned aA1 = (unsigned)(size_t)&As[aB0 + cK1];
    const unsigned bA0 = (unsigned)(size_t)&Bs[bB0 + cK0];
    const unsigned bA1 = (unsigned)(size_t)&Bs[bB0 + cK1];

    short8 aF[4][2], bF0[2], bF1[2];
    f32x4  acc[8][2] = {};

#define VDSR(dst, areg, OFF) \
    asm volatile("ds_read_b128 %0, %1 offset:%2" : "=v"(dst) : "v"(areg), "n"(OFF))

#define VRD_A(DA, QM) do { \
    VDSR(aF[0][0], aA0, (DA) + (QM) * 8192 + 0);    VDSR(aF[0][1], aA1, (DA) + (QM) * 8192 + 0); \
    VDSR(aF[1][0], aA0, (DA) + (QM) * 8192 + 2048); VDSR(aF[1][1], aA1, (DA) + (QM) * 8192 + 2048); \
    VDSR(aF[2][0], aA0, (DA) + (QM) * 8192 + 4096); VDSR(aF[2][1], aA1, (DA) + (QM) * 8192 + 4096); \
    VDSR(aF[3][0], aA0, (DA) + (QM) * 8192 + 6144); VDSR(aF[3][1], aA1, (DA) + (QM) * 8192 + 6144); \
  } while (0)
#define VRD_B(DB, NI, BF) do { \
    VDSR(BF[0], bA0, (DB) + (NI) * 2048); VDSR(BF[1], bA1, (DB) + (NI) * 2048); \
  } while (0)

#define VBAR() asm volatile("s_barrier" ::: "memory")

#define VMM(QM, NI, BF) do { \
    _Pragma("unroll") for (int m2 = 0; m2 < 4; ++m2) { \
        acc[(QM)*4+m2][NI] = __builtin_amdgcn_mfma_f32_16x16x32_bf16( \
            aF[m2][0], BF[0], acc[(QM)*4+m2][NI], 0, 0, 0); \
        acc[(QM)*4+m2][NI] = __builtin_amdgcn_mfma_f32_16x16x32_bf16( \
            aF[m2][1], BF[1], acc[(QM)*4+m2][NI], 0, 0, 0); } \
  } while (0)

#define VTILE(KT, DA, DB) do { \
    if ((KT) + 1 < ktT) { \
        VSTG_A((KT) + 1, 0); VSTG_A((KT) + 1, 1); VSTG_B((KT) + 1); \
    } \
    VRD_A(DA, 0); VRD_B(DB, 0, bF0); VRD_B(DB, 1, bF1); \
    asm volatile("s_waitcnt lgkmcnt(2)"); \
    __builtin_amdgcn_sched_barrier(0); \
    __builtin_amdgcn_s_setprio(1); \
    VMM(0, 0, bF0); \
    asm volatile("s_waitcnt lgkmcnt(0)"); \
    __builtin_amdgcn_sched_barrier(0); \
    VMM(0, 1, bF1); \
    __builtin_amdgcn_s_setprio(0); \
    VRD_A(DA, 1); \
    asm volatile("s_waitcnt lgkmcnt(0)"); \
    __builtin_amdgcn_sched_barrier(0); \
    __builtin_amdgcn_s_setprio(1); \
    VMM(1, 0, bF0); VMM(1, 1, bF1); \
    __builtin_amdgcn_s_setprio(0); \
    asm volatile("s_waitcnt vmcnt(0)"); \
    __builtin_amdgcn_sched_barrier(0); \
    VBAR(); \
  } while (0)

    const int ktT = K >> 6;   // 32

    VSTG_A(0, 0); VSTG_A(0, 1); VSTG_B(0);
    asm volatile("s_waitcnt vmcnt(0)");
    __builtin_amdgcn_sched_barrier(0);
    VBAR();

    for (int kt = 0; kt < ktT; kt += 2) {
        VTILE(kt, 0, 0);
        VTILE(kt + 1, 32768, 16384);
    }

#undef VTILE
#undef VMM
#undef VBAR
#undef VRD_A
#undef VRD_B
#undef VDSR
#undef VSTG_A
#undef VSTG_B

    // ---- epilogue
    #pragma unroll
    for (int mi = 0; mi < 8; ++mi) {
        #pragma unroll
        for (int ni = 0; ni < 2; ++ni) {
            #pragma unroll
            for (int j2 = 0; j2 < 4; ++j2) {
                const int r  = m0 + wr * 128 + mi * 16 + fq * 4 + j2;
                const int cg = n0 + wc * 32 + ni * 16 + fr;
                float v = acc[mi][ni][j2] + bias[cg];
                if (EPI == 0) ((unsigned short*)C)[(size_t)r * ldc + cg] = f2bf(v);
                else          ((float*)C)[(size_t)r * ldc + cg] = v;
            }
        }
    }
}

// ---------------- 128x128 GEMM core (small GEMMs) ----------------
template<int OUT_BF16, int HAS_BIAS>
__device__ __forceinline__ void gemm_tile_core(
    const unsigned short* __restrict__ A, int lda,
    const unsigned short* __restrict__ B, int ldb,
    const float* __restrict__ bias,
    void* __restrict__ Cptr, int ldc, int K)
{
    __shared__ __align__(16) unsigned short As[128 * 64];
    __shared__ __align__(16) unsigned short Bs[128 * 64];

    const int t  = threadIdx.x;
    const int l  = t & 63;
    const int w  = t >> 6;
    const int wr = w >> 1, wc = w & 1;
    const int fr = l & 15, fq = l >> 4;

    f32x4 acc[4][4] = {};

    const int srow = t >> 3;
    const int scol = (t & 7) * 8;

    for (int k0 = 0; k0 < K; k0 += 64) {
        __syncthreads();
        #pragma unroll
        for (int r = 0; r < 4; ++r) {
            gld_lds16(A + (size_t)(r * 32 + srow) * lda + k0 + scol, &As[(r * 32 + srow) * 64 + scol]);
            gld_lds16(B + (size_t)(r * 32 + srow) * ldb + k0 + scol, &Bs[(r * 32 + srow) * 64 + scol]);
        }
        __syncthreads();
        #pragma unroll
        for (int kk = 0; kk < 2; ++kk) {
            short8 a[4], b[4];
            #pragma unroll
            for (int mi = 0; mi < 4; ++mi)
                a[mi] = *(const short8*)&As[(wr * 64 + mi * 16 + fr) * 64 + kk * 32 + fq * 8];
            #pragma unroll
            for (int ni = 0; ni < 4; ++ni)
                b[ni] = *(const short8*)&Bs[(wc * 64 + ni * 16 + fr) * 64 + kk * 32 + fq * 8];
            #pragma unroll
            for (int mi = 0; mi < 4; ++mi)
                #pragma unroll
                for (int ni = 0; ni < 4; ++ni)
                    acc[mi][ni] = __builtin_amdgcn_mfma_f32_16x16x32_bf16(a[mi], b[ni], acc[mi][ni], 0, 0, 0);
        }
    }

    #pragma unroll
    for (int mi = 0; mi < 4; ++mi) {
        #pragma unroll
        for (int ni = 0; ni < 4; ++ni) {
            #pragma unroll
            for (int j = 0; j < 4; ++j) {
                int rr = wr * 64 + mi * 16 + fq * 4 + j;
                int cc = wc * 64 + ni * 16 + fr;
                float v = acc[mi][ni][j];
                if (HAS_BIAS) v += bias[cc];
                if (OUT_BF16) ((unsigned short*)Cptr)[(size_t)rr * ldc + cc] = f2bf(v);
                else          ((float*)Cptr)[(size_t)rr * ldc + cc] = v;
            }
        }
    }
}

// ---------------- K^T/V partials ----------------
__global__ __launch_bounds__(256) void ktv_kernel(
    const unsigned short* __restrict__ QKV, float* __restrict__ part)
{
    const int ks = blockIdx.x;
    const int bh = blockIdx.y;
    const int b = bh >> 4, h = bh & 15;
    const unsigned short* Kbase = QKV + (size_t)(b * SEQ + ks * 256) * NQKV + 2048 + h * HD;
    const unsigned short* Vbase = QKV + (size_t)(b * SEQ + ks * 256) * NQKV + 4096 + h * HD;

    __shared__ __align__(16) unsigned short Ks_[64 * 128];
    __shared__ __align__(16) unsigned short Vs_[64 * 128];

    const int t  = threadIdx.x;
    const int l  = t & 63;
    const int w  = t >> 6;
    const int wr = w >> 1, wc = w & 1;
    const int fr = l & 15, fq = l >> 4;

    f32x4 acc[4][4] = {};

    const int srow = t >> 4;
    const int scol = (t & 15) * 8;

    for (int sc = 0; sc < 4; ++sc) {
        __syncthreads();
        #pragma unroll
        for (int r = 0; r < 4; ++r) {
            gld_lds16(Kbase + (size_t)(sc * 64 + r * 16 + srow) * NQKV + scol, &Ks_[(r * 16 + srow) * 128 + scol]);
            gld_lds16(Vbase + (size_t)(sc * 64 + r * 16 + srow) * NQKV + scol, &Vs_[(r * 16 + srow) * 128 + scol]);
        }
        __syncthreads();
        #pragma unroll
        for (int kk = 0; kk < 2; ++kk) {
            short8 a[4], bb[4];
            #pragma unroll
            for (int mi = 0; mi < 4; ++mi)
                #pragma unroll
                for (int i = 0; i < 8; ++i)
                    a[mi][i] = (short)Ks_[(kk * 32 + fq * 8 + i) * 128 + wr * 64 + mi * 16 + fr];
            #pragma unroll
            for (int ni = 0; ni < 4; ++ni)
                #pragma unroll
                for (int i = 0; i < 8; ++i)
                    bb[ni][i] = (short)Vs_[(kk * 32 + fq * 8 + i) * 128 + wc * 64 + ni * 16 + fr];
            #pragma unroll
            for (int mi = 0; mi < 4; ++mi)
                #pragma unroll
                for (int ni = 0; ni < 4; ++ni)
                    acc[mi][ni] = __builtin_amdgcn_mfma_f32_16x16x32_bf16(a[mi], bb[ni], acc[mi][ni], 0, 0, 0);
        }
    }

    float* base = part + ((size_t)bh * 8 + ks) * 16384;
    #pragma unroll
    for (int mi = 0; mi < 4; ++mi)
        #pragma unroll
        for (int ni = 0; ni < 4; ++ni)
            #pragma unroll
            for (int j = 0; j < 4; ++j)
                base[(wr * 64 + mi * 16 + fq * 4 + j) * 128 + wc * 64 + ni * 16 + fr] = acc[mi][ni][j];
}

// ---------------- reduce partials ----------------
__global__ void ktv_reduce(const float* __restrict__ part, unsigned short* __restrict__ M2t) {
    int idx = blockIdx.x * 256 + threadIdx.x;
    int bh = idx >> 14, rem = idx & 16383;
    const float* p = part + ((size_t)bh * 8) * 16384 + rem;
    float s = 0.f;
    #pragma unroll
    for (int k = 0; k < 8; ++k) s += p[(size_t)k * 16384];
    M2t[idx] = f2bf(s * 0.08838834764831845f);
}

// ---------------- W2 fold ----------------
__global__ __launch_bounds__(256) void w2_gemm(
    const unsigned short* __restrict__ Wo2, const unsigned short* __restrict__ M2t,
    unsigned short* __restrict__ W2)
{
    const int mt = blockIdx.x;
    const int bh = blockIdx.y;
    const int b = bh >> 4, h = bh & 15;
    const unsigned short* A = Wo2 + (size_t)(mt * 128) * DIMN + h * HD;
    const unsigned short* B = M2t + (size_t)bh * HD * HD;
    unsigned short* Cp = W2 + (size_t)b * DIMN * DIMN + (size_t)(mt * 128) * DIMN + h * HD;
    gemm_tile_core<1, 0>(A, DIMN, B, HD, nullptr, Cp, DIMN, HD);
}

extern "C" void kernel_launch(void* const* d_in, const int* in_sizes, int n_in,
                              void* d_out, int out_size, void* d_ws, size_t ws_size,
                              hipStream_t stream) {
    const float* x    = (const float*)d_in[0];
    const float* fcos = (const float*)d_in[1];
    const float* fsin = (const float*)d_in[2];
    const float* wq   = (const float*)d_in[3];
    const float* bq   = (const float*)d_in[4];
    const float* wk   = (const float*)d_in[5];
    const float* bk   = (const float*)d_in[6];
    const float* wv   = (const float*)d_in[7];
    const float* bv   = (const float*)d_in[8];
    const float* wo   = (const float*)d_in[9];
    const float* bo   = (const float*)d_in[10];
    float* out = (float*)d_out;

    char* ws = (char*)d_ws;
    size_t off = 0;
    auto alloc = [&](size_t bytes) { char* p = ws + off; off += (bytes + 255) & ~(size_t)255; return p; };

    unsigned short* Xb   = (unsigned short*)alloc((size_t)ROWS * DIMN * 2);
    unsigned short* Wcat = (unsigned short*)alloc((size_t)NQKV * DIMN * 2);
    unsigned short* Wo2  = (unsigned short*)alloc((size_t)DIMN * DIMN * 2);
    unsigned short* QKV  = (unsigned short*)alloc((size_t)ROWS * NQKV * 2);
    float*          part = (float*)alloc((size_t)32 * 8 * HD * HD * 4);
    unsigned short* M2t  = (unsigned short*)alloc((size_t)32 * HD * HD * 2);
    unsigned short* W2   = (unsigned short*)alloc((size_t)BSZ * DIMN * DIMN * 2);

    // all converts in one launch
    cvt_all<<<24576, 256, 0, stream>>>(x, wq, wk, wv, wo, Xb, Wcat, Wo2);

    // QK projection + bias + RoPE  (M=4096, N=4096, K=2048): 256 blocks
    gemm_qk<<<256, 512, 0, stream>>>(
        Xb, DIMN, Wcat, DIMN, bq, bk, fcos, fsin, QKV, NQKV, DIMN);

    // V projection + bias  (M=4096, N=2048, K=2048): 256 blocks BM256xBN128 (proven ~34us)
    gemm_n128<0><<<256, 512, 0, stream>>>(
        Xb, DIMN, Wcat + (size_t)4096 * DIMN, DIMN, bv, QKV + 4096, NQKV, DIMN);

    // reassociated attention (no softmax): M2t = (K^T V)^T/sqrt(d) per (b,h)
    ktv_kernel<<<dim3(8, 32), 256, 0, stream>>>(QKV, part);
    ktv_reduce<<<(32 * 16384) / 256, 256, 0, stream>>>(part, M2t);

    // fold attention + output projection: W2_b = concat_h(Wo_h @ M2_{b,h})
    w2_gemm<<<dim3(16, 32), 256, 0, stream>>>(Wo2, M2t, W2);

    // out = Q @ W2_b^T + bo  (M=4096, N=2048, K=2048): 256 blocks BM256xBN128 (ported)
    gemm_n128<1><<<256, 512, 0, stream>>>(
        QKV, NQKV, W2, DIMN, bo, out, DIMN, DIMN);
}